// Round 6
// baseline (209.328 us; speedup 1.0000x reference)
//
#include <hip/hip_runtime.h>
#include <hip/hip_bf16.h>

typedef __hip_bfloat16 bf16;
typedef __attribute__((ext_vector_type(8))) short bf16x8;
typedef __attribute__((ext_vector_type(8))) _Float16 f16x8;
typedef __attribute__((ext_vector_type(4))) float f32x4;

constexpr int N_TOK = 2048;
constexpr int DIMM  = 1024;
constexpr int NH    = 16;
constexpr int HD    = 64;
constexpr int FM    = 64;
constexpr int NC    = 32;
constexpr int CS    = 64;

__device__ __forceinline__ float b2f(bf16 v) { return __bfloat162float(v); }
__device__ __forceinline__ unsigned short f2bfu(float v) {
  bf16 h = __float2bfloat16(v);
  return *reinterpret_cast<unsigned short*>(&h);
}
__device__ __forceinline__ unsigned short f2hu(float v) {
  _Float16 h = (_Float16)v;
  return *reinterpret_cast<unsigned short*>(&h);
}

// async global->LDS, 16B per lane. LDS dest = wave-uniform base + lane*16B.
__device__ __forceinline__ void gl_lds16(const void* g, short* l) {
  __builtin_amdgcn_global_load_lds(
      (const __attribute__((address_space(1))) void*)g,
      (__attribute__((address_space(3))) void*)l, 16, 0, 0);
}

__device__ __forceinline__ void split_pack_bf(const float4 v, uint2& ph, uint2& pl) {
  float f[4] = {v.x, v.y, v.z, v.w};
  unsigned short h[4], l[4];
  #pragma unroll
  for (int j = 0; j < 4; j++) {
    bf16 hb = __float2bfloat16(f[j]);
    h[j] = *reinterpret_cast<unsigned short*>(&hb);
    l[j] = f2bfu(f[j] - b2f(hb));
  }
  ph.x = (unsigned)h[0] | ((unsigned)h[1] << 16);
  ph.y = (unsigned)h[2] | ((unsigned)h[3] << 16);
  pl.x = (unsigned)l[0] | ((unsigned)l[1] << 16);
  pl.y = (unsigned)l[2] | ((unsigned)l[3] << 16);
}

// Fused conversions: x -> fp16 hi/lo split; wq|wk|wv -> single fp16; wo -> bf16.
__global__ __launch_bounds__(256) void cvt_all(
    const float4* __restrict__ x, const float4* __restrict__ wq,
    const float4* __restrict__ wk, const float4* __restrict__ wv,
    const float4* __restrict__ wo,
    _Float16* __restrict__ x_hi, _Float16* __restrict__ x_lo,
    _Float16* __restrict__ w16, bf16* __restrict__ wo_bf)
{
  int i = blockIdx.x * 256 + threadIdx.x;   // < 1572864
  if (i < 524288) {            // x -> fp16 hi/lo
    float4 v = x[i];
    float f[4] = {v.x, v.y, v.z, v.w};
    unsigned short h[4], l[4];
    #pragma unroll
    for (int j = 0; j < 4; j++) {
      _Float16 hh = (_Float16)f[j];
      h[j] = *reinterpret_cast<unsigned short*>(&hh);
      l[j] = f2hu(f[j] - (float)hh);
    }
    uint2 ph = { (unsigned)h[0] | ((unsigned)h[1] << 16),
                 (unsigned)h[2] | ((unsigned)h[3] << 16) };
    uint2 pl = { (unsigned)l[0] | ((unsigned)l[1] << 16),
                 (unsigned)l[2] | ((unsigned)l[3] << 16) };
    reinterpret_cast<uint2*>(x_hi)[i] = ph;
    reinterpret_cast<uint2*>(x_lo)[i] = pl;
  } else if (i < 1310720) {    // wq/wk/wv -> fp16
    int j = i - 524288;        // 0 .. 786431, contiguous layout [3072][1024]
    const float4* src = (j < 262144) ? wq : (j < 524288) ? wk : wv;
    int jj = (j < 262144) ? j : (j < 524288) ? j - 262144 : j - 524288;
    float4 v = src[jj];
    uint2 p = { (unsigned)f2hu(v.x) | ((unsigned)f2hu(v.y) << 16),
                (unsigned)f2hu(v.z) | ((unsigned)f2hu(v.w) << 16) };
    reinterpret_cast<uint2*>(w16)[j] = p;
  } else {                     // wo -> bf16
    int j = i - 1310720;
    float4 v = wo[j];
    uint2 p = { (unsigned)f2bfu(v.x) | ((unsigned)f2bfu(v.y) << 16),
                (unsigned)f2bfu(v.z) | ((unsigned)f2bfu(v.w) << 16) };
    reinterpret_cast<uint2*>(wo_bf)[j] = p;
  }
}

// QKV projection: C[n][col] = sum_k (Ah+Al)[n][k] * W[col][k], fp16 2-product MFMA.
// Block 128 rows x 256 cols, BK=32, 4 waves each 64x128. Double-buffered LDS (64 KB).
// Grid (3072/256=12, 2048/128=16) = 192 blocks.
__global__ __launch_bounds__(256, 1) void gemm_qkv_f16(
    const _Float16* __restrict__ Ah, const _Float16* __restrict__ Al,
    const _Float16* __restrict__ B16,
    float* __restrict__ Cq, bf16* __restrict__ Cv)
{
  constexpr int K = 1024;
  __shared__ short sAh[2][4096], sAl[2][4096], sB[2][8192];
  const int tid = threadIdx.x, lane = tid & 63, wv = tid >> 6;
  const int colBase = blockIdx.x * 256, rowBase = blockIdx.y * 128;
  const int waveRow = (wv >> 1) * 64, waveCol = (wv & 1) * 128;
  const int stR = tid >> 2, stK = (tid & 3) * 8;

  const _Float16* gAh = Ah + (size_t)(rowBase + stR) * K + stK;
  const _Float16* gAl = Al + (size_t)(rowBase + stR) * K + stK;
  const _Float16* gB  = B16 + (size_t)(colBase + stR) * K + stK;
  const int ldsOff = wv * 512;   // per-wave LDS chunk within a 2048-elem stage call

  f32x4 acc[4][8];
  #pragma unroll
  for (int r = 0; r < 4; r++)
    #pragma unroll
    for (int c = 0; c < 8; c++) acc[r][c] = (f32x4){0.f, 0.f, 0.f, 0.f};

  const int frow = lane & 15, fk = (lane >> 4) * 8;
  const int nIter = K / 32;

  // prologue: stage iter 0 into buffer 0
  #pragma unroll
  for (int j = 0; j < 2; j++) {
    gl_lds16(gAh + (size_t)(j * 64) * K, &sAh[0][j * 2048 + ldsOff]);
    gl_lds16(gAl + (size_t)(j * 64) * K, &sAl[0][j * 2048 + ldsOff]);
  }
  #pragma unroll
  for (int j = 0; j < 4; j++)
    gl_lds16(gB + (size_t)(j * 64) * K, &sB[0][j * 2048 + ldsOff]);

  int buf = 0;
  for (int it = 0; it < nIter; it++) {
    __syncthreads();
    if (it + 1 < nIter) {
      const size_t kb = (size_t)(it + 1) * 32;
      const int nb = buf ^ 1;
      #pragma unroll
      for (int j = 0; j < 2; j++) {
        gl_lds16(gAh + (size_t)(j * 64) * K + kb, &sAh[nb][j * 2048 + ldsOff]);
        gl_lds16(gAl + (size_t)(j * 64) * K + kb, &sAl[nb][j * 2048 + ldsOff]);
      }
      #pragma unroll
      for (int j = 0; j < 4; j++)
        gl_lds16(gB + (size_t)(j * 64) * K + kb, &sB[nb][j * 2048 + ldsOff]);
    }
    f16x8 ah[4], al[4], b[8];
    #pragma unroll
    for (int r = 0; r < 4; r++) {
      int ro = (waveRow + r * 16 + frow) * 32 + fk;
      ah[r] = *reinterpret_cast<const f16x8*>(&sAh[buf][ro]);
      al[r] = *reinterpret_cast<const f16x8*>(&sAl[buf][ro]);
    }
    #pragma unroll
    for (int c = 0; c < 8; c++) {
      int co = (waveCol + c * 16 + frow) * 32 + fk;
      b[c] = *reinterpret_cast<const f16x8*>(&sB[buf][co]);
    }
    #pragma unroll
    for (int r = 0; r < 4; r++)
      #pragma unroll
      for (int c = 0; c < 8; c++) {
        acc[r][c] = __builtin_amdgcn_mfma_f32_16x16x32_f16(ah[r], b[c], acc[r][c], 0, 0, 0);
        acc[r][c] = __builtin_amdgcn_mfma_f32_16x16x32_f16(al[r], b[c], acc[r][c], 0, 0, 0);
      }
    buf ^= 1;
  }

  #pragma unroll
  for (int r = 0; r < 4; r++)
    #pragma unroll
    for (int c = 0; c < 8; c++)
      #pragma unroll
      for (int reg = 0; reg < 4; reg++) {
        int row = rowBase + waveRow + r * 16 + (lane >> 4) * 4 + reg;
        int col = colBase + waveCol + c * 16 + (lane & 15);
        float v = acc[r][c][reg];
        if (col < 2048) Cq[(size_t)row * 2048 + col] = v;
        else            Cv[(size_t)row * 1024 + (col - 2048)] = __float2bfloat16(v);
      }
}

// Output projection: bf16 NT GEMM + bias, fp32 out. Block 64x128, 4 waves each 32x64,
// dbuf LDS (24 KB). Grid (1024/128=8, 2048/64=32) = 256 blocks.
__global__ __launch_bounds__(256) void gemm_bf16_out(
    const bf16* __restrict__ A, const bf16* __restrict__ B,
    const float* __restrict__ bias, float* __restrict__ C)
{
  constexpr int K = 1024;
  __shared__ short sA[2][2048], sB[2][4096];
  const int tid = threadIdx.x, lane = tid & 63, wv = tid >> 6;
  const int rowBase = blockIdx.y * 64, colBase = blockIdx.x * 128;
  const int waveRow = (wv >> 1) * 32, waveCol = (wv & 1) * 64;
  const int stR = tid >> 2, stK = (tid & 3) * 8;
  const bf16* gA = A + (size_t)(rowBase + stR) * K + stK;
  const bf16* gB = B + (size_t)(colBase + stR) * K + stK;
  const int ldsOff = wv * 512;

  f32x4 acc[2][4];
  #pragma unroll
  for (int r = 0; r < 2; r++)
    #pragma unroll
    for (int c = 0; c < 4; c++) acc[r][c] = (f32x4){0.f, 0.f, 0.f, 0.f};

  const int frow = lane & 15, fk = (lane >> 4) * 8;
  const int nIter = K / 32;

  gl_lds16(gA, &sA[0][ldsOff]);
  gl_lds16(gB, &sB[0][ldsOff]);
  gl_lds16(gB + (size_t)64 * K, &sB[0][2048 + ldsOff]);

  int buf = 0;
  for (int it = 0; it < nIter; it++) {
    __syncthreads();
    if (it + 1 < nIter) {
      const size_t kb = (size_t)(it + 1) * 32;
      const int nb = buf ^ 1;
      gl_lds16(gA + kb, &sA[nb][ldsOff]);
      gl_lds16(gB + kb, &sB[nb][ldsOff]);
      gl_lds16(gB + (size_t)64 * K + kb, &sB[nb][2048 + ldsOff]);
    }
    bf16x8 a[2], b[4];
    #pragma unroll
    for (int r = 0; r < 2; r++)
      a[r] = *reinterpret_cast<const bf16x8*>(&sA[buf][(waveRow + r * 16 + frow) * 32 + fk]);
    #pragma unroll
    for (int c = 0; c < 4; c++)
      b[c] = *reinterpret_cast<const bf16x8*>(&sB[buf][(waveCol + c * 16 + frow) * 32 + fk]);
    #pragma unroll
    for (int r = 0; r < 2; r++)
      #pragma unroll
      for (int c = 0; c < 4; c++)
        acc[r][c] = __builtin_amdgcn_mfma_f32_16x16x32_bf16(a[r], b[c], acc[r][c], 0, 0, 0);
    buf ^= 1;
  }

  #pragma unroll
  for (int r = 0; r < 2; r++)
    #pragma unroll
    for (int c = 0; c < 4; c++)
      #pragma unroll
      for (int reg = 0; reg < 4; reg++) {
        int row = rowBase + waveRow + r * 16 + (lane >> 4) * 4 + reg;
        int col = colBase + waveCol + c * 16 + (lane & 15);
        C[(size_t)row * 1024 + col] = acc[r][c][reg] + bias[col];
      }
}

// MFMA phi: proj = Q_h [128x64] x omega [64x64] (NT), split-bf16, then
// phi = exp(proj - 0.5*||q||^2) / 8, stored bf16 [h][n][m].
__global__ __launch_bounds__(256) void phi_mfma(
    const float* __restrict__ qk, const float* __restrict__ omega,
    bf16* __restrict__ phiq, bf16* __restrict__ phik)
{
  constexpr int LD = 72;
  __shared__ short sAh[128 * LD], sAl[128 * LD];
  __shared__ short sBh[64 * LD],  sBl[64 * LD];
  __shared__ float sPart[128][2];

  const int tid = threadIdx.x, lane = tid & 63, wv = tid >> 6;
  const int n0 = blockIdx.x * 128, h = blockIdx.y, z = blockIdx.z;
  const int colOff = z * 1024 + h * HD;

  {
    const int r = tid >> 1, half = tid & 1;
    const float* src = qk + (size_t)(n0 + r) * 2048 + colOff + half * 32;
    float ssq = 0.f;
    #pragma unroll
    for (int j4 = 0; j4 < 8; j4++) {
      float4 v = reinterpret_cast<const float4*>(src)[j4];
      ssq += v.x * v.x + v.y * v.y + v.z * v.z + v.w * v.w;
      uint2 ph, pl;
      split_pack_bf(v, ph, pl);
      int o = r * LD + half * 32 + j4 * 4;
      *reinterpret_cast<uint2*>(&sAh[o]) = ph;
      *reinterpret_cast<uint2*>(&sAl[o]) = pl;
    }
    sPart[r][half] = ssq;
  }
  {
    const int r = tid >> 2, q4 = tid & 3;
    const float* src = omega + (size_t)r * FM + q4 * 16;
    #pragma unroll
    for (int j4 = 0; j4 < 4; j4++) {
      float4 v = reinterpret_cast<const float4*>(src)[j4];
      uint2 ph, pl;
      split_pack_bf(v, ph, pl);
      int o = r * LD + q4 * 16 + j4 * 4;
      *reinterpret_cast<uint2*>(&sBh[o]) = ph;
      *reinterpret_cast<uint2*>(&sBl[o]) = pl;
    }
  }
  __syncthreads();

  const int waveRow = (wv >> 1) * 64, waveCol = (wv & 1) * 32;
  const int frow = lane & 15, fk = (lane >> 4) * 8;

  f32x4 acc[4][2];
  #pragma unroll
  for (int r = 0; r < 4; r++)
    #pragma unroll
    for (int c = 0; c < 2; c++) acc[r][c] = (f32x4){0.f, 0.f, 0.f, 0.f};

  #pragma unroll
  for (int ks = 0; ks < 64; ks += 32) {
    bf16x8 ah[4], al[4], bh[2], bl[2];
    #pragma unroll
    for (int r = 0; r < 4; r++) {
      int o = (waveRow + r * 16 + frow) * LD + ks + fk;
      ah[r] = *reinterpret_cast<const bf16x8*>(&sAh[o]);
      al[r] = *reinterpret_cast<const bf16x8*>(&sAl[o]);
    }
    #pragma unroll
    for (int c = 0; c < 2; c++) {
      int o = (waveCol + c * 16 + frow) * LD + ks + fk;
      bh[c] = *reinterpret_cast<const bf16x8*>(&sBh[o]);
      bl[c] = *reinterpret_cast<const bf16x8*>(&sBl[o]);
    }
    #pragma unroll
    for (int r = 0; r < 4; r++)
      #pragma unroll
      for (int c = 0; c < 2; c++) {
        acc[r][c] = __builtin_amdgcn_mfma_f32_16x16x32_bf16(ah[r], bh[c], acc[r][c], 0, 0, 0);
        acc[r][c] = __builtin_amdgcn_mfma_f32_16x16x32_bf16(ah[r], bl[c], acc[r][c], 0, 0, 0);
        acc[r][c] = __builtin_amdgcn_mfma_f32_16x16x32_bf16(al[r], bh[c], acc[r][c], 0, 0, 0);
      }
  }

  bf16* dst = z ? phik : phiq;
  #pragma unroll
  for (int r = 0; r < 4; r++)
    #pragma unroll
    for (int c = 0; c < 2; c++)
      #pragma unroll
      for (int reg = 0; reg < 4; reg++) {
        int row = waveRow + r * 16 + (lane >> 4) * 4 + reg;
        int col = waveCol + c * 16 + (lane & 15);
        float norm = 0.5f * (sPart[row][0] + sPart[row][1]);
        float v = __expf(fminf(acc[r][c][reg] - norm, 80.f)) * 0.125f;
        dst[((size_t)h * N_TOK + n0 + row) * FM + col] = __float2bfloat16(v);
      }
}

__global__ __launch_bounds__(256) void chunk_sum(
    const bf16* __restrict__ phik, const bf16* __restrict__ vf,
    float* __restrict__ ckv, float* __restrict__ ck)
{
  const int c = blockIdx.x, h = blockIdx.y;
  __shared__ float sPk[64][65];
  __shared__ float sV[64][65];
  const int tid = threadIdx.x;
  for (int t = tid; t < 4096; t += 256) {
    int j = t >> 6, e = t & 63;
    sPk[j][e] = b2f(phik[((size_t)h * N_TOK + c * CS + j) * FM + e]);
    sV[j][e]  = b2f(vf[(size_t)(c * CS + j) * DIMM + h * HD + e]);
  }
  __syncthreads();
  const int tx = tid & 15, ty = tid >> 4;
  const int m0 = ty * 4, d0 = tx * 4;
  float acc[4][4] = {};
  for (int j = 0; j < 64; j++) {
    float p[4], v[4];
    #pragma unroll
    for (int u = 0; u < 4; u++) { p[u] = sPk[j][m0 + u]; v[u] = sV[j][d0 + u]; }
    #pragma unroll
    for (int u = 0; u < 4; u++)
      #pragma unroll
      for (int w = 0; w < 4; w++) acc[u][w] += p[u] * v[w];
  }
  float* dst = ckv + ((size_t)h * NC + c) * FM * HD;
  #pragma unroll
  for (int u = 0; u < 4; u++)
    #pragma unroll
    for (int w = 0; w < 4; w++) dst[(m0 + u) * HD + d0 + w] = acc[u][w];
  if (tid < 64) {
    float s = 0.f;
    for (int j = 0; j < 64; j++) s += sPk[j][tid];
    ck[((size_t)h * NC + c) * FM + tid] = s;
  }
}

// Register-blocked exclusive prefix over chunks.
__global__ __launch_bounds__(256) void prefix_chunks(
    float* __restrict__ ckv, float* __restrict__ ck)
{
  const int h = blockIdx.x, g = blockIdx.y;
  const int cell = g * 256 + threadIdx.x;
  const size_t base = (size_t)h * NC * 4096 + cell;
  float v[NC];
  #pragma unroll
  for (int c = 0; c < NC; c++) v[c] = ckv[base + (size_t)c * 4096];
  float run = 0.f;
  #pragma unroll
  for (int c = 0; c < NC; c++) { float t = v[c]; ckv[base + (size_t)c * 4096] = run; run += t; }
  if (g == 0 && threadIdx.x < 64) {
    const size_t b2 = (size_t)h * NC * FM + threadIdx.x;
    float u[NC];
    #pragma unroll
    for (int c = 0; c < NC; c++) u[c] = ck[b2 + (size_t)c * FM];
    float r2 = 0.f;
    #pragma unroll
    for (int c = 0; c < NC; c++) { float t = u[c]; ck[b2 + (size_t)c * FM] = r2; r2 += t; }
  }
}

__global__ __launch_bounds__(256) void attn_chunk(
    const bf16* __restrict__ phiq, const bf16* __restrict__ phik,
    const bf16* __restrict__ vf, const float* __restrict__ ckv,
    const float* __restrict__ ck, bf16* __restrict__ attn_out)
{
  const int c = blockIdx.x, h = blockIdx.y;
  __shared__ float sPq[64][65];
  __shared__ float sPk[64][65];
  __shared__ float sV[64][65];
  __shared__ float sS[64][65];
  __shared__ float sKc[64];
  __shared__ float sDen[64];
  const int tid = threadIdx.x;
  const float* ckv_base = ckv + ((size_t)h * NC + c) * 4096;
  for (int t = tid; t < 4096; t += 256) {
    int i = t >> 6, e = t & 63;
    sPq[i][e] = b2f(phiq[((size_t)h * N_TOK + c * CS + i) * FM + e]);
    sPk[i][e] = b2f(phik[((size_t)h * N_TOK + c * CS + i) * FM + e]);
    sV[i][e]  = b2f(vf[(size_t)(c * CS + i) * DIMM + h * HD + e]);
    sS[i][e]  = ckv_base[t];
  }
  if (tid < 64) sKc[tid] = ck[((size_t)h * NC + c) * FM + tid];
  __syncthreads();

  const int tx = tid & 15, ty = tid >> 4;
  const int i0 = ty * 4, j0 = tx * 4;

  float accA[4][4] = {};
  for (int m = 0; m < 64; m++) {
    float a[4], b[4];
    #pragma unroll
    for (int u = 0; u < 4; u++) { a[u] = sPq[i0 + u][m]; b[u] = sPk[j0 + u][m]; }
    #pragma unroll
    for (int u = 0; u < 4; u++)
      #pragma unroll
      for (int w = 0; w < 4; w++) accA[u][w] += a[u] * b[w];
  }
  __syncthreads();
  #pragma unroll
  for (int u = 0; u < 4; u++)
    #pragma unroll
    for (int w = 0; w < 4; w++)
      sPk[i0 + u][j0 + w] = (j0 + w <= i0 + u) ? accA[u][w] : 0.f;
  __syncthreads();

  if (tid < 64) {
    float den = 0.f;
    for (int m = 0; m < 64; m++) den += sPq[tid][m] * sKc[m];
    for (int j = 0; j < 64; j++) den += sPk[tid][j];
    sDen[tid] = 1.f / (den + 1e-6f);
  }
  __syncthreads();

  float accO[4][4] = {};
  for (int j = 0; j < 64; j++) {
    float a[4], v[4];
    #pragma unroll
    for (int u = 0; u < 4; u++) { a[u] = sPk[i0 + u][j]; v[u] = sV[j][j0 + u]; }
    #pragma unroll
    for (int u = 0; u < 4; u++)
      #pragma unroll
      for (int w = 0; w < 4; w++) accO[u][w] += a[u] * v[w];
  }
  for (int m = 0; m < 64; m++) {
    float a[4], s[4];
    #pragma unroll
    for (int u = 0; u < 4; u++) { a[u] = sPq[i0 + u][m]; s[u] = sS[m][j0 + u]; }
    #pragma unroll
    for (int u = 0; u < 4; u++)
      #pragma unroll
      for (int w = 0; w < 4; w++) accO[u][w] += a[u] * s[w];
  }
  #pragma unroll
  for (int u = 0; u < 4; u++) {
    int n = c * CS + i0 + u;
    float inv = sDen[i0 + u];
    uint2 pk2;
    pk2.x = (unsigned)f2bfu(accO[u][0] * inv) | ((unsigned)f2bfu(accO[u][1] * inv) << 16);
    pk2.y = (unsigned)f2bfu(accO[u][2] * inv) | ((unsigned)f2bfu(accO[u][3] * inv) << 16);
    *reinterpret_cast<uint2*>(attn_out + (size_t)n * DIMM + h * HD + j0) = pk2;
  }
}

extern "C" void kernel_launch(void* const* d_in, const int* in_sizes, int n_in,
                              void* d_out, int out_size, void* d_ws, size_t ws_size,
                              hipStream_t stream) {
  (void)in_sizes; (void)n_in; (void)out_size; (void)ws_size;
  const float* x     = (const float*)d_in[0];
  const float* omega = (const float*)d_in[1];
  const float* wq    = (const float*)d_in[2];
  const float* wk    = (const float*)d_in[3];
  const float* wv    = (const float*)d_in[4];
  const float* wo    = (const float*)d_in[5];
  const float* bo    = (const float*)d_in[6];
  float* out = (float*)d_out;

  // Workspace layout, 44 MB total.
  char* w = (char*)d_ws;
  _Float16* x_hi  = (_Float16*)(w);                  // 4 MB  [later: attn bf16 alias]
  _Float16* x_lo  = (_Float16*)(w + (4u  << 20));    // 4 MB
  _Float16* w16   = (_Float16*)(w + (8u  << 20));    // 6 MB  [3072 x 1024]
  bf16*     wo_bf = (bf16*)   (w + (14u << 20));     // 2 MB
  float*    qk    = (float*)  (w + (16u << 20));     // 16 MB [later: ckv+ck alias]
  bf16*     vbf   = (bf16*)   (w + (32u << 20));     // 4 MB
  bf16*     phiq  = (bf16*)   (w + (36u << 20));     // 4 MB
  bf16*     phik  = (bf16*)   (w + (40u << 20));     // 4 MB
  float*    ckv   = (float*)  (w + (16u << 20));     // alias qk (dead after phi)
  float*    ck    = (float*)  (w + (24u << 20));
  bf16*     attnb = (bf16*)x_hi;                     // alias (x_hi dead after QKV GEMM)

  cvt_all<<<6144, 256, 0, stream>>>((const float4*)x, (const float4*)wq,
                                    (const float4*)wk, (const float4*)wv,
                                    (const float4*)wo,
                                    x_hi, x_lo, w16, wo_bf);

  gemm_qkv_f16<<<dim3(12, 16), 256, 0, stream>>>(x_hi, x_lo, w16, qk, vbf);

  phi_mfma<<<dim3(N_TOK / 128, NH, 2), 256, 0, stream>>>(qk, omega, phiq, phik);

  chunk_sum<<<dim3(NC, NH), 256, 0, stream>>>(phik, vbf, ckv, ck);
  prefix_chunks<<<dim3(NH, 16), 256, 0, stream>>>(ckv, ck);
  attn_chunk<<<dim3(NC, NH), 256, 0, stream>>>(phiq, phik, vbf, ckv, ck, attnb);

  gemm_bf16_out<<<dim3(8, 32), 256, 0, stream>>>(attnb, wo_bf, bo, out);
}

// Round 7
// 194.573 us; speedup vs baseline: 1.0758x; 1.0758x over previous
//
#include <hip/hip_runtime.h>
#include <hip/hip_bf16.h>

typedef __hip_bfloat16 bf16;
typedef __attribute__((ext_vector_type(8))) short bf16x8;
typedef __attribute__((ext_vector_type(8))) _Float16 f16x8;
typedef __attribute__((ext_vector_type(4))) float f32x4;

constexpr int N_TOK = 2048;
constexpr int DIMM  = 1024;
constexpr int NH    = 16;
constexpr int HD    = 64;
constexpr int FM    = 64;
constexpr int NC    = 32;
constexpr int CS    = 64;

__device__ __forceinline__ float b2f(bf16 v) { return __bfloat162float(v); }
__device__ __forceinline__ unsigned short f2bfu(float v) {
  bf16 h = __float2bfloat16(v);
  return *reinterpret_cast<unsigned short*>(&h);
}
__device__ __forceinline__ unsigned short f2hu(float v) {
  _Float16 h = (_Float16)v;
  return *reinterpret_cast<unsigned short*>(&h);
}

// async global->LDS, 16B per lane. LDS dest = wave-uniform base + lane*16B.
__device__ __forceinline__ void gl_lds16(const void* g, short* l) {
  __builtin_amdgcn_global_load_lds(
      (const __attribute__((address_space(1))) void*)g,
      (__attribute__((address_space(3))) void*)l, 16, 0, 0);
}

__device__ __forceinline__ void split_pack_bf(const float4 v, uint2& ph, uint2& pl) {
  float f[4] = {v.x, v.y, v.z, v.w};
  unsigned short h[4], l[4];
  #pragma unroll
  for (int j = 0; j < 4; j++) {
    bf16 hb = __float2bfloat16(f[j]);
    h[j] = *reinterpret_cast<unsigned short*>(&hb);
    l[j] = f2bfu(f[j] - b2f(hb));
  }
  ph.x = (unsigned)h[0] | ((unsigned)h[1] << 16);
  ph.y = (unsigned)h[2] | ((unsigned)h[3] << 16);
  pl.x = (unsigned)l[0] | ((unsigned)l[1] << 16);
  pl.y = (unsigned)l[2] | ((unsigned)l[3] << 16);
}

// Fused conversions: x -> fp16 hi/lo split; wq|wk|wv -> single fp16; wo -> bf16.
__global__ __launch_bounds__(256) void cvt_all(
    const float4* __restrict__ x, const float4* __restrict__ wq,
    const float4* __restrict__ wk, const float4* __restrict__ wv,
    const float4* __restrict__ wo,
    _Float16* __restrict__ x_hi, _Float16* __restrict__ x_lo,
    _Float16* __restrict__ w16, bf16* __restrict__ wo_bf)
{
  int i = blockIdx.x * 256 + threadIdx.x;   // < 1572864
  if (i < 524288) {            // x -> fp16 hi/lo
    float4 v = x[i];
    float f[4] = {v.x, v.y, v.z, v.w};
    unsigned short h[4], l[4];
    #pragma unroll
    for (int j = 0; j < 4; j++) {
      _Float16 hh = (_Float16)f[j];
      h[j] = *reinterpret_cast<unsigned short*>(&hh);
      l[j] = f2hu(f[j] - (float)hh);
    }
    uint2 ph = { (unsigned)h[0] | ((unsigned)h[1] << 16),
                 (unsigned)h[2] | ((unsigned)h[3] << 16) };
    uint2 pl = { (unsigned)l[0] | ((unsigned)l[1] << 16),
                 (unsigned)l[2] | ((unsigned)l[3] << 16) };
    reinterpret_cast<uint2*>(x_hi)[i] = ph;
    reinterpret_cast<uint2*>(x_lo)[i] = pl;
  } else if (i < 1310720) {    // wq/wk/wv -> fp16, contiguous [3072][1024]
    int j = i - 524288;
    const float4* src = (j < 262144) ? wq : (j < 524288) ? wk : wv;
    int jj = (j < 262144) ? j : (j < 524288) ? j - 262144 : j - 524288;
    float4 v = src[jj];
    uint2 p = { (unsigned)f2hu(v.x) | ((unsigned)f2hu(v.y) << 16),
                (unsigned)f2hu(v.z) | ((unsigned)f2hu(v.w) << 16) };
    reinterpret_cast<uint2*>(w16)[j] = p;
  } else {                     // wo -> bf16
    int j = i - 1310720;
    float4 v = wo[j];
    uint2 p = { (unsigned)f2bfu(v.x) | ((unsigned)f2bfu(v.y) << 16),
                (unsigned)f2bfu(v.z) | ((unsigned)f2bfu(v.w) << 16) };
    reinterpret_cast<uint2*>(wo_bf)[j] = p;
  }
}

// QKV projection: C[n][col] = sum_k (Ah+Al)[n][k] * W[col][k], fp16 2-product MFMA.
// Block 128x128, BK=32, 4 waves each 64x64, dbuf LDS (48 KB).
// Grid (3072/128=24, 2048/128=16) = 384 blocks (~1.5/CU, up to 3/CU by LDS).
__global__ __launch_bounds__(256) void gemm_qkv_f16(
    const _Float16* __restrict__ Ah, const _Float16* __restrict__ Al,
    const _Float16* __restrict__ B16,
    float* __restrict__ Cq, bf16* __restrict__ Cv)
{
  constexpr int K = 1024;
  __shared__ short sAh[2][4096], sAl[2][4096], sB[2][4096];
  const int tid = threadIdx.x, lane = tid & 63, wv = tid >> 6;
  const int colBase = blockIdx.x * 128, rowBase = blockIdx.y * 128;
  const int waveRow = (wv >> 1) * 64, waveCol = (wv & 1) * 64;
  const int stR = tid >> 2, stK = (tid & 3) * 8;

  const _Float16* gAh = Ah + (size_t)(rowBase + stR) * K + stK;
  const _Float16* gAl = Al + (size_t)(rowBase + stR) * K + stK;
  const _Float16* gB  = B16 + (size_t)(colBase + stR) * K + stK;
  const int ldsOff0 = wv * 512, ldsOff1 = 2048 + wv * 512;

  f32x4 acc[4][4];
  #pragma unroll
  for (int r = 0; r < 4; r++)
    #pragma unroll
    for (int c = 0; c < 4; c++) acc[r][c] = (f32x4){0.f, 0.f, 0.f, 0.f};

  const int frow = lane & 15, fk = (lane >> 4) * 8;
  const int nIter = K / 32;

  // prologue: stage iter 0 into buffer 0
  gl_lds16(gAh, &sAh[0][ldsOff0]); gl_lds16(gAh + (size_t)64 * K, &sAh[0][ldsOff1]);
  gl_lds16(gAl, &sAl[0][ldsOff0]); gl_lds16(gAl + (size_t)64 * K, &sAl[0][ldsOff1]);
  gl_lds16(gB,  &sB[0][ldsOff0]);  gl_lds16(gB  + (size_t)64 * K, &sB[0][ldsOff1]);

  int buf = 0;
  for (int it = 0; it < nIter; it++) {
    __syncthreads();
    if (it + 1 < nIter) {
      const size_t kb = (size_t)(it + 1) * 32;
      const int nb = buf ^ 1;
      gl_lds16(gAh + kb, &sAh[nb][ldsOff0]); gl_lds16(gAh + (size_t)64 * K + kb, &sAh[nb][ldsOff1]);
      gl_lds16(gAl + kb, &sAl[nb][ldsOff0]); gl_lds16(gAl + (size_t)64 * K + kb, &sAl[nb][ldsOff1]);
      gl_lds16(gB  + kb, &sB[nb][ldsOff0]);  gl_lds16(gB  + (size_t)64 * K + kb, &sB[nb][ldsOff1]);
    }
    f16x8 ah[4], al[4], b[4];
    #pragma unroll
    for (int r = 0; r < 4; r++) {
      int ro = (waveRow + r * 16 + frow) * 32 + fk;
      ah[r] = *reinterpret_cast<const f16x8*>(&sAh[buf][ro]);
      al[r] = *reinterpret_cast<const f16x8*>(&sAl[buf][ro]);
    }
    #pragma unroll
    for (int c = 0; c < 4; c++) {
      int co = (waveCol + c * 16 + frow) * 32 + fk;
      b[c] = *reinterpret_cast<const f16x8*>(&sB[buf][co]);
    }
    #pragma unroll
    for (int r = 0; r < 4; r++)
      #pragma unroll
      for (int c = 0; c < 4; c++) {
        acc[r][c] = __builtin_amdgcn_mfma_f32_16x16x32_f16(ah[r], b[c], acc[r][c], 0, 0, 0);
        acc[r][c] = __builtin_amdgcn_mfma_f32_16x16x32_f16(al[r], b[c], acc[r][c], 0, 0, 0);
      }
    buf ^= 1;
  }

  #pragma unroll
  for (int r = 0; r < 4; r++)
    #pragma unroll
    for (int c = 0; c < 4; c++)
      #pragma unroll
      for (int reg = 0; reg < 4; reg++) {
        int row = rowBase + waveRow + r * 16 + (lane >> 4) * 4 + reg;
        int col = colBase + waveCol + c * 16 + (lane & 15);
        float v = acc[r][c][reg];
        if (col < 2048) Cq[(size_t)row * 2048 + col] = v;
        else            Cv[(size_t)row * 1024 + (col - 2048)] = __float2bfloat16(v);
      }
}

// Output projection: bf16 NT GEMM + bias, fp32 out. Block 64x128, 4 waves each 32x64,
// dbuf LDS (24 KB). Grid (8, 32) = 256 blocks.
__global__ __launch_bounds__(256) void gemm_bf16_out(
    const bf16* __restrict__ A, const bf16* __restrict__ B,
    const float* __restrict__ bias, float* __restrict__ C)
{
  constexpr int K = 1024;
  __shared__ short sA[2][2048], sB[2][4096];
  const int tid = threadIdx.x, lane = tid & 63, wv = tid >> 6;
  const int rowBase = blockIdx.y * 64, colBase = blockIdx.x * 128;
  const int waveRow = (wv >> 1) * 32, waveCol = (wv & 1) * 64;
  const int stR = tid >> 2, stK = (tid & 3) * 8;
  const bf16* gA = A + (size_t)(rowBase + stR) * K + stK;
  const bf16* gB = B + (size_t)(colBase + stR) * K + stK;
  const int ldsOff = wv * 512;

  f32x4 acc[2][4];
  #pragma unroll
  for (int r = 0; r < 2; r++)
    #pragma unroll
    for (int c = 0; c < 4; c++) acc[r][c] = (f32x4){0.f, 0.f, 0.f, 0.f};

  const int frow = lane & 15, fk = (lane >> 4) * 8;
  const int nIter = K / 32;

  gl_lds16(gA, &sA[0][ldsOff]);
  gl_lds16(gB, &sB[0][ldsOff]);
  gl_lds16(gB + (size_t)64 * K, &sB[0][2048 + ldsOff]);

  int buf = 0;
  for (int it = 0; it < nIter; it++) {
    __syncthreads();
    if (it + 1 < nIter) {
      const size_t kb = (size_t)(it + 1) * 32;
      const int nb = buf ^ 1;
      gl_lds16(gA + kb, &sA[nb][ldsOff]);
      gl_lds16(gB + kb, &sB[nb][ldsOff]);
      gl_lds16(gB + (size_t)64 * K + kb, &sB[nb][2048 + ldsOff]);
    }
    bf16x8 a[2], b[4];
    #pragma unroll
    for (int r = 0; r < 2; r++)
      a[r] = *reinterpret_cast<const bf16x8*>(&sA[buf][(waveRow + r * 16 + frow) * 32 + fk]);
    #pragma unroll
    for (int c = 0; c < 4; c++)
      b[c] = *reinterpret_cast<const bf16x8*>(&sB[buf][(waveCol + c * 16 + frow) * 32 + fk]);
    #pragma unroll
    for (int r = 0; r < 2; r++)
      #pragma unroll
      for (int c = 0; c < 4; c++)
        acc[r][c] = __builtin_amdgcn_mfma_f32_16x16x32_bf16(a[r], b[c], acc[r][c], 0, 0, 0);
    buf ^= 1;
  }

  #pragma unroll
  for (int r = 0; r < 2; r++)
    #pragma unroll
    for (int c = 0; c < 4; c++)
      #pragma unroll
      for (int reg = 0; reg < 4; reg++) {
        int row = rowBase + waveRow + r * 16 + (lane >> 4) * 4 + reg;
        int col = colBase + waveCol + c * 16 + (lane & 15);
        C[(size_t)row * 1024 + col] = acc[r][c][reg] + bias[col];
      }
}

// MFMA phi: proj = Q_h [128x64] x omega [64x64] (NT), split-bf16, then
// phi = exp(proj - 0.5*||q||^2) / 8, stored bf16 [h][n][m].
__global__ __launch_bounds__(256) void phi_mfma(
    const float* __restrict__ qk, const float* __restrict__ omega,
    bf16* __restrict__ phiq, bf16* __restrict__ phik)
{
  constexpr int LD = 72;
  __shared__ short sAh[128 * LD], sAl[128 * LD];
  __shared__ short sBh[64 * LD],  sBl[64 * LD];
  __shared__ float sPart[128][2];

  const int tid = threadIdx.x, lane = tid & 63, wv = tid >> 6;
  const int n0 = blockIdx.x * 128, h = blockIdx.y, z = blockIdx.z;
  const int colOff = z * 1024 + h * HD;

  {
    const int r = tid >> 1, half = tid & 1;
    const float* src = qk + (size_t)(n0 + r) * 2048 + colOff + half * 32;
    float ssq = 0.f;
    #pragma unroll
    for (int j4 = 0; j4 < 8; j4++) {
      float4 v = reinterpret_cast<const float4*>(src)[j4];
      ssq += v.x * v.x + v.y * v.y + v.z * v.z + v.w * v.w;
      uint2 ph, pl;
      split_pack_bf(v, ph, pl);
      int o = r * LD + half * 32 + j4 * 4;
      *reinterpret_cast<uint2*>(&sAh[o]) = ph;
      *reinterpret_cast<uint2*>(&sAl[o]) = pl;
    }
    sPart[r][half] = ssq;
  }
  {
    const int r = tid >> 2, q4 = tid & 3;
    const float* src = omega + (size_t)r * FM + q4 * 16;
    #pragma unroll
    for (int j4 = 0; j4 < 4; j4++) {
      float4 v = reinterpret_cast<const float4*>(src)[j4];
      uint2 ph, pl;
      split_pack_bf(v, ph, pl);
      int o = r * LD + q4 * 16 + j4 * 4;
      *reinterpret_cast<uint2*>(&sBh[o]) = ph;
      *reinterpret_cast<uint2*>(&sBl[o]) = pl;
    }
  }
  __syncthreads();

  const int waveRow = (wv >> 1) * 64, waveCol = (wv & 1) * 32;
  const int frow = lane & 15, fk = (lane >> 4) * 8;

  f32x4 acc[4][2];
  #pragma unroll
  for (int r = 0; r < 4; r++)
    #pragma unroll
    for (int c = 0; c < 2; c++) acc[r][c] = (f32x4){0.f, 0.f, 0.f, 0.f};

  #pragma unroll
  for (int ks = 0; ks < 64; ks += 32) {
    bf16x8 ah[4], al[4], bh[2], bl[2];
    #pragma unroll
    for (int r = 0; r < 4; r++) {
      int o = (waveRow + r * 16 + frow) * LD + ks + fk;
      ah[r] = *reinterpret_cast<const bf16x8*>(&sAh[o]);
      al[r] = *reinterpret_cast<const bf16x8*>(&sAl[o]);
    }
    #pragma unroll
    for (int c = 0; c < 2; c++) {
      int o = (waveCol + c * 16 + frow) * LD + ks + fk;
      bh[c] = *reinterpret_cast<const bf16x8*>(&sBh[o]);
      bl[c] = *reinterpret_cast<const bf16x8*>(&sBl[o]);
    }
    #pragma unroll
    for (int r = 0; r < 4; r++)
      #pragma unroll
      for (int c = 0; c < 2; c++) {
        acc[r][c] = __builtin_amdgcn_mfma_f32_16x16x32_bf16(ah[r], bh[c], acc[r][c], 0, 0, 0);
        acc[r][c] = __builtin_amdgcn_mfma_f32_16x16x32_bf16(ah[r], bl[c], acc[r][c], 0, 0, 0);
        acc[r][c] = __builtin_amdgcn_mfma_f32_16x16x32_bf16(al[r], bh[c], acc[r][c], 0, 0, 0);
      }
  }

  bf16* dst = z ? phik : phiq;
  #pragma unroll
  for (int r = 0; r < 4; r++)
    #pragma unroll
    for (int c = 0; c < 2; c++)
      #pragma unroll
      for (int reg = 0; reg < 4; reg++) {
        int row = waveRow + r * 16 + (lane >> 4) * 4 + reg;
        int col = waveCol + c * 16 + (lane & 15);
        float norm = 0.5f * (sPart[row][0] + sPart[row][1]);
        float v = __expf(fminf(acc[r][c][reg] - norm, 80.f)) * 0.125f;
        dst[((size_t)h * N_TOK + n0 + row) * FM + col] = __float2bfloat16(v);
      }
}

__global__ __launch_bounds__(256) void chunk_sum(
    const bf16* __restrict__ phik, const bf16* __restrict__ vf,
    float* __restrict__ ckv, float* __restrict__ ck)
{
  const int c = blockIdx.x, h = blockIdx.y;
  __shared__ float sPk[64][65];
  __shared__ float sV[64][65];
  const int tid = threadIdx.x;
  for (int t = tid; t < 4096; t += 256) {
    int j = t >> 6, e = t & 63;
    sPk[j][e] = b2f(phik[((size_t)h * N_TOK + c * CS + j) * FM + e]);
    sV[j][e]  = b2f(vf[(size_t)(c * CS + j) * DIMM + h * HD + e]);
  }
  __syncthreads();
  const int tx = tid & 15, ty = tid >> 4;
  const int m0 = ty * 4, d0 = tx * 4;
  float acc[4][4] = {};
  for (int j = 0; j < 64; j++) {
    float p[4], v[4];
    #pragma unroll
    for (int u = 0; u < 4; u++) { p[u] = sPk[j][m0 + u]; v[u] = sV[j][d0 + u]; }
    #pragma unroll
    for (int u = 0; u < 4; u++)
      #pragma unroll
      for (int w = 0; w < 4; w++) acc[u][w] += p[u] * v[w];
  }
  float* dst = ckv + ((size_t)h * NC + c) * FM * HD;
  #pragma unroll
  for (int u = 0; u < 4; u++)
    #pragma unroll
    for (int w = 0; w < 4; w++) dst[(m0 + u) * HD + d0 + w] = acc[u][w];
  if (tid < 64) {
    float s = 0.f;
    for (int j = 0; j < 64; j++) s += sPk[j][tid];
    ck[((size_t)h * NC + c) * FM + tid] = s;
  }
}

// Register-blocked exclusive prefix over chunks.
__global__ __launch_bounds__(256) void prefix_chunks(
    float* __restrict__ ckv, float* __restrict__ ck)
{
  const int h = blockIdx.x, g = blockIdx.y;
  const int cell = g * 256 + threadIdx.x;
  const size_t base = (size_t)h * NC * 4096 + cell;
  float v[NC];
  #pragma unroll
  for (int c = 0; c < NC; c++) v[c] = ckv[base + (size_t)c * 4096];
  float run = 0.f;
  #pragma unroll
  for (int c = 0; c < NC; c++) { float t = v[c]; ckv[base + (size_t)c * 4096] = run; run += t; }
  if (g == 0 && threadIdx.x < 64) {
    const size_t b2 = (size_t)h * NC * FM + threadIdx.x;
    float u[NC];
    #pragma unroll
    for (int c = 0; c < NC; c++) u[c] = ck[b2 + (size_t)c * FM];
    float r2 = 0.f;
    #pragma unroll
    for (int c = 0; c < NC; c++) { float t = u[c]; ck[b2 + (size_t)c * FM] = r2; r2 += t; }
  }
}

__global__ __launch_bounds__(256) void attn_chunk(
    const bf16* __restrict__ phiq, const bf16* __restrict__ phik,
    const bf16* __restrict__ vf, const float* __restrict__ ckv,
    const float* __restrict__ ck, bf16* __restrict__ attn_out)
{
  const int c = blockIdx.x, h = blockIdx.y;
  __shared__ float sPq[64][65];
  __shared__ float sPk[64][65];
  __shared__ float sV[64][65];
  __shared__ float sS[64][65];
  __shared__ float sKc[64];
  __shared__ float sDen[64];
  const int tid = threadIdx.x;
  const float* ckv_base = ckv + ((size_t)h * NC + c) * 4096;
  for (int t = tid; t < 4096; t += 256) {
    int i = t >> 6, e = t & 63;
    sPq[i][e] = b2f(phiq[((size_t)h * N_TOK + c * CS + i) * FM + e]);
    sPk[i][e] = b2f(phik[((size_t)h * N_TOK + c * CS + i) * FM + e]);
    sV[i][e]  = b2f(vf[(size_t)(c * CS + i) * DIMM + h * HD + e]);
    sS[i][e]  = ckv_base[t];
  }
  if (tid < 64) sKc[tid] = ck[((size_t)h * NC + c) * FM + tid];
  __syncthreads();

  const int tx = tid & 15, ty = tid >> 4;
  const int i0 = ty * 4, j0 = tx * 4;

  float accA[4][4] = {};
  for (int m = 0; m < 64; m++) {
    float a[4], b[4];
    #pragma unroll
    for (int u = 0; u < 4; u++) { a[u] = sPq[i0 + u][m]; b[u] = sPk[j0 + u][m]; }
    #pragma unroll
    for (int u = 0; u < 4; u++)
      #pragma unroll
      for (int w = 0; w < 4; w++) accA[u][w] += a[u] * b[w];
  }
  __syncthreads();
  #pragma unroll
  for (int u = 0; u < 4; u++)
    #pragma unroll
    for (int w = 0; w < 4; w++)
      sPk[i0 + u][j0 + w] = (j0 + w <= i0 + u) ? accA[u][w] : 0.f;
  __syncthreads();

  if (tid < 64) {
    float den = 0.f;
    for (int m = 0; m < 64; m++) den += sPq[tid][m] * sKc[m];
    for (int j = 0; j < 64; j++) den += sPk[tid][j];
    sDen[tid] = 1.f / (den + 1e-6f);
  }
  __syncthreads();

  float accO[4][4] = {};
  for (int j = 0; j < 64; j++) {
    float a[4], v[4];
    #pragma unroll
    for (int u = 0; u < 4; u++) { a[u] = sPk[i0 + u][j]; v[u] = sV[j][j0 + u]; }
    #pragma unroll
    for (int u = 0; u < 4; u++)
      #pragma unroll
      for (int w = 0; w < 4; w++) accO[u][w] += a[u] * v[w];
  }
  for (int m = 0; m < 64; m++) {
    float a[4], s[4];
    #pragma unroll
    for (int u = 0; u < 4; u++) { a[u] = sPq[i0 + u][m]; s[u] = sS[m][j0 + u]; }
    #pragma unroll
    for (int u = 0; u < 4; u++)
      #pragma unroll
      for (int w = 0; w < 4; w++) accO[u][w] += a[u] * s[w];
  }
  #pragma unroll
  for (int u = 0; u < 4; u++) {
    int n = c * CS + i0 + u;
    float inv = sDen[i0 + u];
    uint2 pk2;
    pk2.x = (unsigned)f2bfu(accO[u][0] * inv) | ((unsigned)f2bfu(accO[u][1] * inv) << 16);
    pk2.y = (unsigned)f2bfu(accO[u][2] * inv) | ((unsigned)f2bfu(accO[u][3] * inv) << 16);
    *reinterpret_cast<uint2*>(attn_out + (size_t)n * DIMM + h * HD + j0) = pk2;
  }
}

extern "C" void kernel_launch(void* const* d_in, const int* in_sizes, int n_in,
                              void* d_out, int out_size, void* d_ws, size_t ws_size,
                              hipStream_t stream) {
  (void)in_sizes; (void)n_in; (void)out_size; (void)ws_size;
  const float* x     = (const float*)d_in[0];
  const float* omega = (const float*)d_in[1];
  const float* wq    = (const float*)d_in[2];
  const float* wk    = (const float*)d_in[3];
  const float* wv    = (const float*)d_in[4];
  const float* wo    = (const float*)d_in[5];
  const float* bo    = (const float*)d_in[6];
  float* out = (float*)d_out;

  // Workspace layout, 44 MB total.
  char* w = (char*)d_ws;
  _Float16* x_hi  = (_Float16*)(w);                  // 4 MB  [later: attn bf16 alias]
  _Float16* x_lo  = (_Float16*)(w + (4u  << 20));    // 4 MB
  _Float16* w16   = (_Float16*)(w + (8u  << 20));    // 6 MB  [3072 x 1024]
  bf16*     wo_bf = (bf16*)   (w + (14u << 20));     // 2 MB
  float*    qk    = (float*)  (w + (16u << 20));     // 16 MB [later: ckv+ck alias]
  bf16*     vbf   = (bf16*)   (w + (32u << 20));     // 4 MB
  bf16*     phiq  = (bf16*)   (w + (36u << 20));     // 4 MB
  bf16*     phik  = (bf16*)   (w + (40u << 20));     // 4 MB
  float*    ckv   = (float*)  (w + (16u << 20));     // alias qk (dead after phi)
  float*    ck    = (float*)  (w + (24u << 20));
  bf16*     attnb = (bf16*)x_hi;                     // alias (x_hi dead after QKV GEMM)

  cvt_all<<<6144, 256, 0, stream>>>((const float4*)x, (const float4*)wq,
                                    (const float4*)wk, (const float4*)wv,
                                    (const float4*)wo,
                                    x_hi, x_lo, w16, wo_bf);

  gemm_qkv_f16<<<dim3(24, 16), 256, 0, stream>>>(x_hi, x_lo, w16, qk, vbf);

  phi_mfma<<<dim3(N_TOK / 128, NH, 2), 256, 0, stream>>>(qk, omega, phiq, phik);

  chunk_sum<<<dim3(NC, NH), 256, 0, stream>>>(phik, vbf, ckv, ck);
  prefix_chunks<<<dim3(NH, 16), 256, 0, stream>>>(ckv, ck);
  attn_chunk<<<dim3(NC, NH), 256, 0, stream>>>(phiq, phik, vbf, ckv, ck, attnb);

  gemm_bf16_out<<<dim3(8, 32), 256, 0, stream>>>(attnb, wo_bf, bo, out);
}

// Round 8
// 174.286 us; speedup vs baseline: 1.2011x; 1.1164x over previous
//
#include <hip/hip_runtime.h>
#include <hip/hip_bf16.h>

typedef __hip_bfloat16 bf16;
typedef __attribute__((ext_vector_type(8))) short bf16x8;
typedef __attribute__((ext_vector_type(8))) _Float16 f16x8;
typedef __attribute__((ext_vector_type(4))) float f32x4;

constexpr int N_TOK = 2048;
constexpr int DIMM  = 1024;
constexpr int NH    = 16;
constexpr int HD    = 64;
constexpr int FM    = 64;
constexpr int NC    = 32;
constexpr int CS    = 64;

__device__ __forceinline__ float b2f(bf16 v) { return __bfloat162float(v); }
__device__ __forceinline__ unsigned short f2bfu(float v) {
  bf16 h = __float2bfloat16(v);
  return *reinterpret_cast<unsigned short*>(&h);
}
__device__ __forceinline__ unsigned short f2hu(float v) {
  _Float16 h = (_Float16)v;
  return *reinterpret_cast<unsigned short*>(&h);
}

// async global->LDS, 16B per lane. LDS dest = wave-uniform base + lane*16B.
__device__ __forceinline__ void gl_lds16(const void* g, short* l) {
  __builtin_amdgcn_global_load_lds(
      (const __attribute__((address_space(1))) void*)g,
      (__attribute__((address_space(3))) void*)l, 16, 0, 0);
}

__device__ __forceinline__ void split_pack_bf(const float4 v, uint2& ph, uint2& pl) {
  float f[4] = {v.x, v.y, v.z, v.w};
  unsigned short h[4], l[4];
  #pragma unroll
  for (int j = 0; j < 4; j++) {
    bf16 hb = __float2bfloat16(f[j]);
    h[j] = *reinterpret_cast<unsigned short*>(&hb);
    l[j] = f2bfu(f[j] - b2f(hb));
  }
  ph.x = (unsigned)h[0] | ((unsigned)h[1] << 16);
  ph.y = (unsigned)h[2] | ((unsigned)h[3] << 16);
  pl.x = (unsigned)l[0] | ((unsigned)l[1] << 16);
  pl.y = (unsigned)l[2] | ((unsigned)l[3] << 16);
}

// Fused conversions: x -> fp16; wq|wk|wv -> fp16 [3072][1024]; wo -> bf16.
__global__ __launch_bounds__(256) void cvt_all(
    const float4* __restrict__ x, const float4* __restrict__ wq,
    const float4* __restrict__ wk, const float4* __restrict__ wv,
    const float4* __restrict__ wo,
    _Float16* __restrict__ x16, _Float16* __restrict__ w16,
    bf16* __restrict__ wo_bf)
{
  int i = blockIdx.x * 256 + threadIdx.x;   // < 1572864
  if (i < 524288) {            // x -> fp16
    float4 v = x[i];
    uint2 p = { (unsigned)f2hu(v.x) | ((unsigned)f2hu(v.y) << 16),
                (unsigned)f2hu(v.z) | ((unsigned)f2hu(v.w) << 16) };
    reinterpret_cast<uint2*>(x16)[i] = p;
  } else if (i < 1310720) {    // wq/wk/wv -> fp16
    int j = i - 524288;
    const float4* src = (j < 262144) ? wq : (j < 524288) ? wk : wv;
    int jj = (j < 262144) ? j : (j < 524288) ? j - 262144 : j - 524288;
    float4 v = src[jj];
    uint2 p = { (unsigned)f2hu(v.x) | ((unsigned)f2hu(v.y) << 16),
                (unsigned)f2hu(v.z) | ((unsigned)f2hu(v.w) << 16) };
    reinterpret_cast<uint2*>(w16)[j] = p;
  } else {                     // wo -> bf16
    int j = i - 1310720;
    float4 v = wo[j];
    uint2 p = { (unsigned)f2bfu(v.x) | ((unsigned)f2bfu(v.y) << 16),
                (unsigned)f2bfu(v.z) | ((unsigned)f2bfu(v.w) << 16) };
    reinterpret_cast<uint2*>(wo_bf)[j] = p;
  }
}

// QKV projection: C[n][col] = sum_k A[n][k] * W[col][k], single fp16 MFMA product.
// Block 128x128, BK=32, 4 waves each 64x64, dbuf LDS (32 KB). Grid 24x16=384.
// q/k cols (<2048) -> fp16 qk buffer; v cols -> bf16.
__global__ __launch_bounds__(256) void gemm_qkv_f16(
    const _Float16* __restrict__ A16, const _Float16* __restrict__ B16,
    _Float16* __restrict__ Cq, bf16* __restrict__ Cv)
{
  constexpr int K = 1024;
  __shared__ short sA[2][4096], sB[2][4096];
  const int tid = threadIdx.x, lane = tid & 63, wv = tid >> 6;
  const int colBase = blockIdx.x * 128, rowBase = blockIdx.y * 128;
  const int waveRow = (wv >> 1) * 64, waveCol = (wv & 1) * 64;
  const int stR = tid >> 2, stK = (tid & 3) * 8;

  const _Float16* gA = A16 + (size_t)(rowBase + stR) * K + stK;
  const _Float16* gB = B16 + (size_t)(colBase + stR) * K + stK;
  const int ldsOff0 = wv * 512, ldsOff1 = 2048 + wv * 512;

  f32x4 acc[4][4];
  #pragma unroll
  for (int r = 0; r < 4; r++)
    #pragma unroll
    for (int c = 0; c < 4; c++) acc[r][c] = (f32x4){0.f, 0.f, 0.f, 0.f};

  const int frow = lane & 15, fk = (lane >> 4) * 8;
  const int nIter = K / 32;

  gl_lds16(gA, &sA[0][ldsOff0]); gl_lds16(gA + (size_t)64 * K, &sA[0][ldsOff1]);
  gl_lds16(gB, &sB[0][ldsOff0]); gl_lds16(gB + (size_t)64 * K, &sB[0][ldsOff1]);

  int buf = 0;
  for (int it = 0; it < nIter; it++) {
    __syncthreads();
    if (it + 1 < nIter) {
      const size_t kb = (size_t)(it + 1) * 32;
      const int nb = buf ^ 1;
      gl_lds16(gA + kb, &sA[nb][ldsOff0]); gl_lds16(gA + (size_t)64 * K + kb, &sA[nb][ldsOff1]);
      gl_lds16(gB + kb, &sB[nb][ldsOff0]); gl_lds16(gB + (size_t)64 * K + kb, &sB[nb][ldsOff1]);
    }
    f16x8 a[4], b[4];
    #pragma unroll
    for (int r = 0; r < 4; r++)
      a[r] = *reinterpret_cast<const f16x8*>(&sA[buf][(waveRow + r * 16 + frow) * 32 + fk]);
    #pragma unroll
    for (int c = 0; c < 4; c++)
      b[c] = *reinterpret_cast<const f16x8*>(&sB[buf][(waveCol + c * 16 + frow) * 32 + fk]);
    #pragma unroll
    for (int r = 0; r < 4; r++)
      #pragma unroll
      for (int c = 0; c < 4; c++)
        acc[r][c] = __builtin_amdgcn_mfma_f32_16x16x32_f16(a[r], b[c], acc[r][c], 0, 0, 0);
    buf ^= 1;
  }

  #pragma unroll
  for (int r = 0; r < 4; r++)
    #pragma unroll
    for (int c = 0; c < 4; c++)
      #pragma unroll
      for (int reg = 0; reg < 4; reg++) {
        int row = rowBase + waveRow + r * 16 + (lane >> 4) * 4 + reg;
        int col = colBase + waveCol + c * 16 + (lane & 15);
        float v = acc[r][c][reg];
        if (col < 2048) Cq[(size_t)row * 2048 + col] = (_Float16)v;
        else            Cv[(size_t)row * 1024 + (col - 2048)] = __float2bfloat16(v);
      }
}

// Output projection: bf16 NT GEMM + bias, fp32 out. Block 64x128, dbuf LDS.
__global__ __launch_bounds__(256) void gemm_bf16_out(
    const bf16* __restrict__ A, const bf16* __restrict__ B,
    const float* __restrict__ bias, float* __restrict__ C)
{
  constexpr int K = 1024;
  __shared__ short sA[2][2048], sB[2][4096];
  const int tid = threadIdx.x, lane = tid & 63, wv = tid >> 6;
  const int rowBase = blockIdx.y * 64, colBase = blockIdx.x * 128;
  const int waveRow = (wv >> 1) * 32, waveCol = (wv & 1) * 64;
  const int stR = tid >> 2, stK = (tid & 3) * 8;
  const bf16* gA = A + (size_t)(rowBase + stR) * K + stK;
  const bf16* gB = B + (size_t)(colBase + stR) * K + stK;
  const int ldsOff = wv * 512;

  f32x4 acc[2][4];
  #pragma unroll
  for (int r = 0; r < 2; r++)
    #pragma unroll
    for (int c = 0; c < 4; c++) acc[r][c] = (f32x4){0.f, 0.f, 0.f, 0.f};

  const int frow = lane & 15, fk = (lane >> 4) * 8;
  const int nIter = K / 32;

  gl_lds16(gA, &sA[0][ldsOff]);
  gl_lds16(gB, &sB[0][ldsOff]);
  gl_lds16(gB + (size_t)64 * K, &sB[0][2048 + ldsOff]);

  int buf = 0;
  for (int it = 0; it < nIter; it++) {
    __syncthreads();
    if (it + 1 < nIter) {
      const size_t kb = (size_t)(it + 1) * 32;
      const int nb = buf ^ 1;
      gl_lds16(gA + kb, &sA[nb][ldsOff]);
      gl_lds16(gB + kb, &sB[nb][ldsOff]);
      gl_lds16(gB + (size_t)64 * K + kb, &sB[nb][2048 + ldsOff]);
    }
    bf16x8 a[2], b[4];
    #pragma unroll
    for (int r = 0; r < 2; r++)
      a[r] = *reinterpret_cast<const bf16x8*>(&sA[buf][(waveRow + r * 16 + frow) * 32 + fk]);
    #pragma unroll
    for (int c = 0; c < 4; c++)
      b[c] = *reinterpret_cast<const bf16x8*>(&sB[buf][(waveCol + c * 16 + frow) * 32 + fk]);
    #pragma unroll
    for (int r = 0; r < 2; r++)
      #pragma unroll
      for (int c = 0; c < 4; c++)
        acc[r][c] = __builtin_amdgcn_mfma_f32_16x16x32_bf16(a[r], b[c], acc[r][c], 0, 0, 0);
    buf ^= 1;
  }

  #pragma unroll
  for (int r = 0; r < 2; r++)
    #pragma unroll
    for (int c = 0; c < 4; c++)
      #pragma unroll
      for (int reg = 0; reg < 4; reg++) {
        int row = rowBase + waveRow + r * 16 + (lane >> 4) * 4 + reg;
        int col = colBase + waveCol + c * 16 + (lane & 15);
        C[(size_t)row * 1024 + col] = acc[r][c][reg] + bias[col];
      }
}

// MFMA phi from fp16 qk: proj = Q_h x omega^T (split-bf16 of the fp16 values),
// phi = exp(proj - 0.5*||q||^2)/8, stored bf16 [h][n][m].
__global__ __launch_bounds__(256) void phi_mfma(
    const _Float16* __restrict__ qk, const float* __restrict__ omega,
    bf16* __restrict__ phiq, bf16* __restrict__ phik)
{
  constexpr int LD = 72;
  __shared__ short sAh[128 * LD], sAl[128 * LD];
  __shared__ short sBh[64 * LD],  sBl[64 * LD];
  __shared__ float sPart[128][2];

  const int tid = threadIdx.x, lane = tid & 63, wv = tid >> 6;
  const int n0 = blockIdx.x * 128, h = blockIdx.y, z = blockIdx.z;
  const int colOff = z * 1024 + h * HD;

  {
    const int r = tid >> 1, half = tid & 1;
    const _Float16* src = qk + (size_t)(n0 + r) * 2048 + colOff + half * 32;
    float ssq = 0.f;
    #pragma unroll
    for (int j8 = 0; j8 < 4; j8++) {
      uint4 raw = reinterpret_cast<const uint4*>(src)[j8];   // 8 fp16
      const unsigned short* hs = reinterpret_cast<const unsigned short*>(&raw);
      unsigned short hh[8], ll[8];
      #pragma unroll
      for (int j = 0; j < 8; j++) {
        _Float16 hv;
        *reinterpret_cast<unsigned short*>(&hv) = hs[j];
        float f = (float)hv;
        ssq += f * f;
        bf16 hb = __float2bfloat16(f);
        hh[j] = *reinterpret_cast<unsigned short*>(&hb);
        ll[j] = f2bfu(f - b2f(hb));
      }
      int o = r * LD + half * 32 + j8 * 8;
      uint4 ph = { (unsigned)hh[0] | ((unsigned)hh[1] << 16),
                   (unsigned)hh[2] | ((unsigned)hh[3] << 16),
                   (unsigned)hh[4] | ((unsigned)hh[5] << 16),
                   (unsigned)hh[6] | ((unsigned)hh[7] << 16) };
      uint4 pl = { (unsigned)ll[0] | ((unsigned)ll[1] << 16),
                   (unsigned)ll[2] | ((unsigned)ll[3] << 16),
                   (unsigned)ll[4] | ((unsigned)ll[5] << 16),
                   (unsigned)ll[6] | ((unsigned)ll[7] << 16) };
      *reinterpret_cast<uint4*>(&sAh[o]) = ph;
      *reinterpret_cast<uint4*>(&sAl[o]) = pl;
    }
    sPart[r][half] = ssq;
  }
  {
    const int r = tid >> 2, q4 = tid & 3;
    const float* src = omega + (size_t)r * FM + q4 * 16;
    #pragma unroll
    for (int j4 = 0; j4 < 4; j4++) {
      float4 v = reinterpret_cast<const float4*>(src)[j4];
      uint2 ph, pl;
      split_pack_bf(v, ph, pl);
      int o = r * LD + q4 * 16 + j4 * 4;
      *reinterpret_cast<uint2*>(&sBh[o]) = ph;
      *reinterpret_cast<uint2*>(&sBl[o]) = pl;
    }
  }
  __syncthreads();

  const int waveRow = (wv >> 1) * 64, waveCol = (wv & 1) * 32;
  const int frow = lane & 15, fk = (lane >> 4) * 8;

  f32x4 acc[4][2];
  #pragma unroll
  for (int r = 0; r < 4; r++)
    #pragma unroll
    for (int c = 0; c < 2; c++) acc[r][c] = (f32x4){0.f, 0.f, 0.f, 0.f};

  #pragma unroll
  for (int ks = 0; ks < 64; ks += 32) {
    bf16x8 ah[4], al[4], bh[2], bl[2];
    #pragma unroll
    for (int r = 0; r < 4; r++) {
      int o = (waveRow + r * 16 + frow) * LD + ks + fk;
      ah[r] = *reinterpret_cast<const bf16x8*>(&sAh[o]);
      al[r] = *reinterpret_cast<const bf16x8*>(&sAl[o]);
    }
    #pragma unroll
    for (int c = 0; c < 2; c++) {
      int o = (waveCol + c * 16 + frow) * LD + ks + fk;
      bh[c] = *reinterpret_cast<const bf16x8*>(&sBh[o]);
      bl[c] = *reinterpret_cast<const bf16x8*>(&sBl[o]);
    }
    #pragma unroll
    for (int r = 0; r < 4; r++)
      #pragma unroll
      for (int c = 0; c < 2; c++) {
        acc[r][c] = __builtin_amdgcn_mfma_f32_16x16x32_bf16(ah[r], bh[c], acc[r][c], 0, 0, 0);
        acc[r][c] = __builtin_amdgcn_mfma_f32_16x16x32_bf16(ah[r], bl[c], acc[r][c], 0, 0, 0);
        acc[r][c] = __builtin_amdgcn_mfma_f32_16x16x32_bf16(al[r], bh[c], acc[r][c], 0, 0, 0);
      }
  }

  bf16* dst = z ? phik : phiq;
  #pragma unroll
  for (int r = 0; r < 4; r++)
    #pragma unroll
    for (int c = 0; c < 2; c++)
      #pragma unroll
      for (int reg = 0; reg < 4; reg++) {
        int row = waveRow + r * 16 + (lane >> 4) * 4 + reg;
        int col = waveCol + c * 16 + (lane & 15);
        float norm = 0.5f * (sPart[row][0] + sPart[row][1]);
        float v = __expf(fminf(acc[r][c][reg] - norm, 80.f)) * 0.125f;
        dst[((size_t)h * N_TOK + n0 + row) * FM + col] = __float2bfloat16(v);
      }
}

__global__ __launch_bounds__(256) void chunk_sum(
    const bf16* __restrict__ phik, const bf16* __restrict__ vf,
    float* __restrict__ ckv, float* __restrict__ ck)
{
  const int c = blockIdx.x, h = blockIdx.y;
  __shared__ float sPk[64][65];
  __shared__ float sV[64][65];
  const int tid = threadIdx.x;
  for (int t = tid; t < 4096; t += 256) {
    int j = t >> 6, e = t & 63;
    sPk[j][e] = b2f(phik[((size_t)h * N_TOK + c * CS + j) * FM + e]);
    sV[j][e]  = b2f(vf[(size_t)(c * CS + j) * DIMM + h * HD + e]);
  }
  __syncthreads();
  const int tx = tid & 15, ty = tid >> 4;
  const int m0 = ty * 4, d0 = tx * 4;
  float acc[4][4] = {};
  for (int j = 0; j < 64; j++) {
    float p[4], v[4];
    #pragma unroll
    for (int u = 0; u < 4; u++) { p[u] = sPk[j][m0 + u]; v[u] = sV[j][d0 + u]; }
    #pragma unroll
    for (int u = 0; u < 4; u++)
      #pragma unroll
      for (int w = 0; w < 4; w++) acc[u][w] += p[u] * v[w];
  }
  float* dst = ckv + ((size_t)h * NC + c) * FM * HD;
  #pragma unroll
  for (int u = 0; u < 4; u++)
    #pragma unroll
    for (int w = 0; w < 4; w++) dst[(m0 + u) * HD + d0 + w] = acc[u][w];
  if (tid < 64) {
    float s = 0.f;
    for (int j = 0; j < 64; j++) s += sPk[j][tid];
    ck[((size_t)h * NC + c) * FM + tid] = s;
  }
}

// Register-blocked exclusive prefix over chunks.
__global__ __launch_bounds__(256) void prefix_chunks(
    float* __restrict__ ckv, float* __restrict__ ck)
{
  const int h = blockIdx.x, g = blockIdx.y;
  const int cell = g * 256 + threadIdx.x;
  const size_t base = (size_t)h * NC * 4096 + cell;
  float v[NC];
  #pragma unroll
  for (int c = 0; c < NC; c++) v[c] = ckv[base + (size_t)c * 4096];
  float run = 0.f;
  #pragma unroll
  for (int c = 0; c < NC; c++) { float t = v[c]; ckv[base + (size_t)c * 4096] = run; run += t; }
  if (g == 0 && threadIdx.x < 64) {
    const size_t b2 = (size_t)h * NC * FM + threadIdx.x;
    float u[NC];
    #pragma unroll
    for (int c = 0; c < NC; c++) u[c] = ck[b2 + (size_t)c * FM];
    float r2 = 0.f;
    #pragma unroll
    for (int c = 0; c < NC; c++) { float t = u[c]; ck[b2 + (size_t)c * FM] = r2; r2 += t; }
  }
}

__global__ __launch_bounds__(256) void attn_chunk(
    const bf16* __restrict__ phiq, const bf16* __restrict__ phik,
    const bf16* __restrict__ vf, const float* __restrict__ ckv,
    const float* __restrict__ ck, bf16* __restrict__ attn_out)
{
  const int c = blockIdx.x, h = blockIdx.y;
  __shared__ float sPq[64][65];
  __shared__ float sPk[64][65];
  __shared__ float sV[64][65];
  __shared__ float sS[64][65];
  __shared__ float sKc[64];
  __shared__ float sDen[64];
  const int tid = threadIdx.x;
  const float* ckv_base = ckv + ((size_t)h * NC + c) * 4096;
  for (int t = tid; t < 4096; t += 256) {
    int i = t >> 6, e = t & 63;
    sPq[i][e] = b2f(phiq[((size_t)h * N_TOK + c * CS + i) * FM + e]);
    sPk[i][e] = b2f(phik[((size_t)h * N_TOK + c * CS + i) * FM + e]);
    sV[i][e]  = b2f(vf[(size_t)(c * CS + i) * DIMM + h * HD + e]);
    sS[i][e]  = ckv_base[t];
  }
  if (tid < 64) sKc[tid] = ck[((size_t)h * NC + c) * FM + tid];
  __syncthreads();

  const int tx = tid & 15, ty = tid >> 4;
  const int i0 = ty * 4, j0 = tx * 4;

  float accA[4][4] = {};
  for (int m = 0; m < 64; m++) {
    float a[4], b[4];
    #pragma unroll
    for (int u = 0; u < 4; u++) { a[u] = sPq[i0 + u][m]; b[u] = sPk[j0 + u][m]; }
    #pragma unroll
    for (int u = 0; u < 4; u++)
      #pragma unroll
      for (int w = 0; w < 4; w++) accA[u][w] += a[u] * b[w];
  }
  __syncthreads();
  #pragma unroll
  for (int u = 0; u < 4; u++)
    #pragma unroll
    for (int w = 0; w < 4; w++)
      sPk[i0 + u][j0 + w] = (j0 + w <= i0 + u) ? accA[u][w] : 0.f;
  __syncthreads();

  if (tid < 64) {
    float den = 0.f;
    for (int m = 0; m < 64; m++) den += sPq[tid][m] * sKc[m];
    for (int j = 0; j < 64; j++) den += sPk[tid][j];
    sDen[tid] = 1.f / (den + 1e-6f);
  }
  __syncthreads();

  float accO[4][4] = {};
  for (int j = 0; j < 64; j++) {
    float a[4], v[4];
    #pragma unroll
    for (int u = 0; u < 4; u++) { a[u] = sPk[i0 + u][j]; v[u] = sV[j][j0 + u]; }
    #pragma unroll
    for (int u = 0; u < 4; u++)
      #pragma unroll
      for (int w = 0; w < 4; w++) accO[u][w] += a[u] * v[w];
  }
  for (int m = 0; m < 64; m++) {
    float a[4], s[4];
    #pragma unroll
    for (int u = 0; u < 4; u++) { a[u] = sPq[i0 + u][m]; s[u] = sS[m][j0 + u]; }
    #pragma unroll
    for (int u = 0; u < 4; u++)
      #pragma unroll
      for (int w = 0; w < 4; w++) accO[u][w] += a[u] * s[w];
  }
  #pragma unroll
  for (int u = 0; u < 4; u++) {
    int n = c * CS + i0 + u;
    float inv = sDen[i0 + u];
    uint2 pk2;
    pk2.x = (unsigned)f2bfu(accO[u][0] * inv) | ((unsigned)f2bfu(accO[u][1] * inv) << 16);
    pk2.y = (unsigned)f2bfu(accO[u][2] * inv) | ((unsigned)f2bfu(accO[u][3] * inv) << 16);
    *reinterpret_cast<uint2*>(attn_out + (size_t)n * DIMM + h * HD + j0) = pk2;
  }
}

extern "C" void kernel_launch(void* const* d_in, const int* in_sizes, int n_in,
                              void* d_out, int out_size, void* d_ws, size_t ws_size,
                              hipStream_t stream) {
  (void)in_sizes; (void)n_in; (void)out_size; (void)ws_size;
  const float* x     = (const float*)d_in[0];
  const float* omega = (const float*)d_in[1];
  const float* wq    = (const float*)d_in[2];
  const float* wk    = (const float*)d_in[3];
  const float* wv    = (const float*)d_in[4];
  const float* wo    = (const float*)d_in[5];
  const float* bo    = (const float*)d_in[6];
  float* out = (float*)d_out;

  // Workspace layout, ~40.2 MB total.
  char* w = (char*)d_ws;
  _Float16* x16   = (_Float16*)(w);                  // 4 MB  [later: attn bf16 alias]
  _Float16* w16   = (_Float16*)(w + (4u  << 20));    // 6 MB  [3072 x 1024]
  bf16*     wo_bf = (bf16*)   (w + (10u << 20));     // 2 MB
  _Float16* qk    = (_Float16*)(w + (12u << 20));    // 8 MB  [2048 x 2048]
  bf16*     vbf   = (bf16*)   (w + (20u << 20));     // 4 MB
  bf16*     phiq  = (bf16*)   (w + (24u << 20));     // 4 MB
  bf16*     phik  = (bf16*)   (w + (28u << 20));     // 4 MB
  float*    ckv   = (float*)  (w + (32u << 20));     // 8 MB
  float*    ck    = (float*)  (w + (40u << 20));     // 128 KB
  bf16*     attnb = (bf16*)x16;                      // alias (x16 dead after QKV GEMM)

  cvt_all<<<6144, 256, 0, stream>>>((const float4*)x, (const float4*)wq,
                                    (const float4*)wk, (const float4*)wv,
                                    (const float4*)wo,
                                    x16, w16, wo_bf);

  gemm_qkv_f16<<<dim3(24, 16), 256, 0, stream>>>(x16, w16, qk, vbf);

  phi_mfma<<<dim3(N_TOK / 128, NH, 2), 256, 0, stream>>>(qk, omega, phiq, phik);

  chunk_sum<<<dim3(NC, NH), 256, 0, stream>>>(phik, vbf, ckv, ck);
  prefix_chunks<<<dim3(NH, 16), 256, 0, stream>>>(ckv, ck);
  attn_chunk<<<dim3(NC, NH), 256, 0, stream>>>(phiq, phik, vbf, ckv, ck, attnb);

  gemm_bf16_out<<<dim3(8, 32), 256, 0, stream>>>(attnb, wo_bf, bo, out);
}

// Round 9
// 151.663 us; speedup vs baseline: 1.3802x; 1.1492x over previous
//
#include <hip/hip_runtime.h>
#include <hip/hip_bf16.h>

typedef __hip_bfloat16 bf16;
typedef __attribute__((ext_vector_type(8))) short bf16x8;
typedef __attribute__((ext_vector_type(8))) _Float16 f16x8;
typedef __attribute__((ext_vector_type(4))) float f32x4;

constexpr int N_TOK = 2048;
constexpr int DIMM  = 1024;
constexpr int NH    = 16;
constexpr int HD    = 64;
constexpr int FM    = 64;
constexpr int NC    = 32;
constexpr int CS    = 64;

__device__ __forceinline__ float b2f(bf16 v) { return __bfloat162float(v); }
__device__ __forceinline__ unsigned short f2bfu(float v) {
  bf16 h = __float2bfloat16(v);
  return *reinterpret_cast<unsigned short*>(&h);
}
__device__ __forceinline__ unsigned short f2hu(float v) {
  _Float16 h = (_Float16)v;
  return *reinterpret_cast<unsigned short*>(&h);
}

__device__ __forceinline__ void gl_lds16(const void* g, short* l) {
  __builtin_amdgcn_global_load_lds(
      (const __attribute__((address_space(1))) void*)g,
      (__attribute__((address_space(3))) void*)l, 16, 0, 0);
}

__device__ __forceinline__ void split_pack_bf(const float4 v, uint2& ph, uint2& pl) {
  float f[4] = {v.x, v.y, v.z, v.w};
  unsigned short h[4], l[4];
  #pragma unroll
  for (int j = 0; j < 4; j++) {
    bf16 hb = __float2bfloat16(f[j]);
    h[j] = *reinterpret_cast<unsigned short*>(&hb);
    l[j] = f2bfu(f[j] - b2f(hb));
  }
  ph.x = (unsigned)h[0] | ((unsigned)h[1] << 16);
  ph.y = (unsigned)h[2] | ((unsigned)h[3] << 16);
  pl.x = (unsigned)l[0] | ((unsigned)l[1] << 16);
  pl.y = (unsigned)l[2] | ((unsigned)l[3] << 16);
}

// Fused conversions: x -> fp16; wq|wk|wv -> fp16 [3072][1024]; wo -> bf16.
__global__ __launch_bounds__(256) void cvt_all(
    const float4* __restrict__ x, const float4* __restrict__ wq,
    const float4* __restrict__ wk, const float4* __restrict__ wv,
    const float4* __restrict__ wo,
    _Float16* __restrict__ x16, _Float16* __restrict__ w16,
    bf16* __restrict__ wo_bf)
{
  int i = blockIdx.x * 256 + threadIdx.x;   // < 1572864
  if (i < 524288) {
    float4 v = x[i];
    uint2 p = { (unsigned)f2hu(v.x) | ((unsigned)f2hu(v.y) << 16),
                (unsigned)f2hu(v.z) | ((unsigned)f2hu(v.w) << 16) };
    reinterpret_cast<uint2*>(x16)[i] = p;
  } else if (i < 1310720) {
    int j = i - 524288;
    const float4* src = (j < 262144) ? wq : (j < 524288) ? wk : wv;
    int jj = (j < 262144) ? j : (j < 524288) ? j - 262144 : j - 524288;
    float4 v = src[jj];
    uint2 p = { (unsigned)f2hu(v.x) | ((unsigned)f2hu(v.y) << 16),
                (unsigned)f2hu(v.z) | ((unsigned)f2hu(v.w) << 16) };
    reinterpret_cast<uint2*>(w16)[j] = p;
  } else {
    int j = i - 1310720;
    float4 v = wo[j];
    uint2 p = { (unsigned)f2bfu(v.x) | ((unsigned)f2bfu(v.y) << 16),
                (unsigned)f2bfu(v.z) | ((unsigned)f2bfu(v.w) << 16) };
    reinterpret_cast<uint2*>(wo_bf)[j] = p;
  }
}

// QKV projection: single fp16 MFMA product. Block 128x128, BK=32, dbuf. Grid 24x16.
__global__ __launch_bounds__(256) void gemm_qkv_f16(
    const _Float16* __restrict__ A16, const _Float16* __restrict__ B16,
    _Float16* __restrict__ Cq, bf16* __restrict__ Cv)
{
  constexpr int K = 1024;
  __shared__ short sA[2][4096], sB[2][4096];
  const int tid = threadIdx.x, lane = tid & 63, wv = tid >> 6;
  const int colBase = blockIdx.x * 128, rowBase = blockIdx.y * 128;
  const int waveRow = (wv >> 1) * 64, waveCol = (wv & 1) * 64;
  const int stR = tid >> 2, stK = (tid & 3) * 8;

  const _Float16* gA = A16 + (size_t)(rowBase + stR) * K + stK;
  const _Float16* gB = B16 + (size_t)(colBase + stR) * K + stK;
  const int ldsOff0 = wv * 512, ldsOff1 = 2048 + wv * 512;

  f32x4 acc[4][4];
  #pragma unroll
  for (int r = 0; r < 4; r++)
    #pragma unroll
    for (int c = 0; c < 4; c++) acc[r][c] = (f32x4){0.f, 0.f, 0.f, 0.f};

  const int frow = lane & 15, fk = (lane >> 4) * 8;
  const int nIter = K / 32;

  gl_lds16(gA, &sA[0][ldsOff0]); gl_lds16(gA + (size_t)64 * K, &sA[0][ldsOff1]);
  gl_lds16(gB, &sB[0][ldsOff0]); gl_lds16(gB + (size_t)64 * K, &sB[0][ldsOff1]);

  int buf = 0;
  for (int it = 0; it < nIter; it++) {
    __syncthreads();
    if (it + 1 < nIter) {
      const size_t kb = (size_t)(it + 1) * 32;
      const int nb = buf ^ 1;
      gl_lds16(gA + kb, &sA[nb][ldsOff0]); gl_lds16(gA + (size_t)64 * K + kb, &sA[nb][ldsOff1]);
      gl_lds16(gB + kb, &sB[nb][ldsOff0]); gl_lds16(gB + (size_t)64 * K + kb, &sB[nb][ldsOff1]);
    }
    f16x8 a[4], b[4];
    #pragma unroll
    for (int r = 0; r < 4; r++)
      a[r] = *reinterpret_cast<const f16x8*>(&sA[buf][(waveRow + r * 16 + frow) * 32 + fk]);
    #pragma unroll
    for (int c = 0; c < 4; c++)
      b[c] = *reinterpret_cast<const f16x8*>(&sB[buf][(waveCol + c * 16 + frow) * 32 + fk]);
    #pragma unroll
    for (int r = 0; r < 4; r++)
      #pragma unroll
      for (int c = 0; c < 4; c++)
        acc[r][c] = __builtin_amdgcn_mfma_f32_16x16x32_f16(a[r], b[c], acc[r][c], 0, 0, 0);
    buf ^= 1;
  }

  #pragma unroll
  for (int r = 0; r < 4; r++)
    #pragma unroll
    for (int c = 0; c < 4; c++)
      #pragma unroll
      for (int reg = 0; reg < 4; reg++) {
        int row = rowBase + waveRow + r * 16 + (lane >> 4) * 4 + reg;
        int col = colBase + waveCol + c * 16 + (lane & 15);
        float v = acc[r][c][reg];
        if (col < 2048) Cq[(size_t)row * 2048 + col] = (_Float16)v;
        else            Cv[(size_t)row * 1024 + (col - 2048)] = __float2bfloat16(v);
      }
}

// Output projection: bf16 NT GEMM + bias, fp32 out. Block 64x128, dbuf LDS.
__global__ __launch_bounds__(256) void gemm_bf16_out(
    const bf16* __restrict__ A, const bf16* __restrict__ B,
    const float* __restrict__ bias, float* __restrict__ C)
{
  constexpr int K = 1024;
  __shared__ short sA[2][2048], sB[2][4096];
  const int tid = threadIdx.x, lane = tid & 63, wv = tid >> 6;
  const int rowBase = blockIdx.y * 64, colBase = blockIdx.x * 128;
  const int waveRow = (wv >> 1) * 32, waveCol = (wv & 1) * 64;
  const int stR = tid >> 2, stK = (tid & 3) * 8;
  const bf16* gA = A + (size_t)(rowBase + stR) * K + stK;
  const bf16* gB = B + (size_t)(colBase + stR) * K + stK;
  const int ldsOff = wv * 512;

  f32x4 acc[2][4];
  #pragma unroll
  for (int r = 0; r < 2; r++)
    #pragma unroll
    for (int c = 0; c < 4; c++) acc[r][c] = (f32x4){0.f, 0.f, 0.f, 0.f};

  const int frow = lane & 15, fk = (lane >> 4) * 8;
  const int nIter = K / 32;

  gl_lds16(gA, &sA[0][ldsOff]);
  gl_lds16(gB, &sB[0][ldsOff]);
  gl_lds16(gB + (size_t)64 * K, &sB[0][2048 + ldsOff]);

  int buf = 0;
  for (int it = 0; it < nIter; it++) {
    __syncthreads();
    if (it + 1 < nIter) {
      const size_t kb = (size_t)(it + 1) * 32;
      const int nb = buf ^ 1;
      gl_lds16(gA + kb, &sA[nb][ldsOff]);
      gl_lds16(gB + kb, &sB[nb][ldsOff]);
      gl_lds16(gB + (size_t)64 * K + kb, &sB[nb][2048 + ldsOff]);
    }
    bf16x8 a[2], b[4];
    #pragma unroll
    for (int r = 0; r < 2; r++)
      a[r] = *reinterpret_cast<const bf16x8*>(&sA[buf][(waveRow + r * 16 + frow) * 32 + fk]);
    #pragma unroll
    for (int c = 0; c < 4; c++)
      b[c] = *reinterpret_cast<const bf16x8*>(&sB[buf][(waveCol + c * 16 + frow) * 32 + fk]);
    #pragma unroll
    for (int r = 0; r < 2; r++)
      #pragma unroll
      for (int c = 0; c < 4; c++)
        acc[r][c] = __builtin_amdgcn_mfma_f32_16x16x32_bf16(a[r], b[c], acc[r][c], 0, 0, 0);
    buf ^= 1;
  }

  #pragma unroll
  for (int r = 0; r < 2; r++)
    #pragma unroll
    for (int c = 0; c < 4; c++)
      #pragma unroll
      for (int reg = 0; reg < 4; reg++) {
        int row = rowBase + waveRow + r * 16 + (lane >> 4) * 4 + reg;
        int col = colBase + waveCol + c * 16 + (lane & 15);
        C[(size_t)row * 1024 + col] = acc[r][c][reg] + bias[col];
      }
}

// MFMA phi from fp16 qk: phi = exp(q.omega - 0.5||q||^2)/8, bf16 out [h][n][m].
__global__ __launch_bounds__(256) void phi_mfma(
    const _Float16* __restrict__ qk, const float* __restrict__ omega,
    bf16* __restrict__ phiq, bf16* __restrict__ phik)
{
  constexpr int LD = 72;
  __shared__ short sAh[128 * LD], sAl[128 * LD];
  __shared__ short sBh[64 * LD],  sBl[64 * LD];
  __shared__ float sPart[128][2];

  const int tid = threadIdx.x, lane = tid & 63, wv = tid >> 6;
  const int n0 = blockIdx.x * 128, h = blockIdx.y, z = blockIdx.z;
  const int colOff = z * 1024 + h * HD;

  {
    const int r = tid >> 1, half = tid & 1;
    const _Float16* src = qk + (size_t)(n0 + r) * 2048 + colOff + half * 32;
    float ssq = 0.f;
    #pragma unroll
    for (int j8 = 0; j8 < 4; j8++) {
      uint4 raw = reinterpret_cast<const uint4*>(src)[j8];
      const unsigned short* hs = reinterpret_cast<const unsigned short*>(&raw);
      unsigned short hh[8], ll[8];
      #pragma unroll
      for (int j = 0; j < 8; j++) {
        _Float16 hv;
        *reinterpret_cast<unsigned short*>(&hv) = hs[j];
        float f = (float)hv;
        ssq += f * f;
        bf16 hb = __float2bfloat16(f);
        hh[j] = *reinterpret_cast<unsigned short*>(&hb);
        ll[j] = f2bfu(f - b2f(hb));
      }
      int o = r * LD + half * 32 + j8 * 8;
      uint4 ph = { (unsigned)hh[0] | ((unsigned)hh[1] << 16),
                   (unsigned)hh[2] | ((unsigned)hh[3] << 16),
                   (unsigned)hh[4] | ((unsigned)hh[5] << 16),
                   (unsigned)hh[6] | ((unsigned)hh[7] << 16) };
      uint4 pl = { (unsigned)ll[0] | ((unsigned)ll[1] << 16),
                   (unsigned)ll[2] | ((unsigned)ll[3] << 16),
                   (unsigned)ll[4] | ((unsigned)ll[5] << 16),
                   (unsigned)ll[6] | ((unsigned)ll[7] << 16) };
      *reinterpret_cast<uint4*>(&sAh[o]) = ph;
      *reinterpret_cast<uint4*>(&sAl[o]) = pl;
    }
    sPart[r][half] = ssq;
  }
  {
    const int r = tid >> 2, q4 = tid & 3;
    const float* src = omega + (size_t)r * FM + q4 * 16;
    #pragma unroll
    for (int j4 = 0; j4 < 4; j4++) {
      float4 v = reinterpret_cast<const float4*>(src)[j4];
      uint2 ph, pl;
      split_pack_bf(v, ph, pl);
      int o = r * LD + q4 * 16 + j4 * 4;
      *reinterpret_cast<uint2*>(&sBh[o]) = ph;
      *reinterpret_cast<uint2*>(&sBl[o]) = pl;
    }
  }
  __syncthreads();

  const int waveRow = (wv >> 1) * 64, waveCol = (wv & 1) * 32;
  const int frow = lane & 15, fk = (lane >> 4) * 8;

  f32x4 acc[4][2];
  #pragma unroll
  for (int r = 0; r < 4; r++)
    #pragma unroll
    for (int c = 0; c < 2; c++) acc[r][c] = (f32x4){0.f, 0.f, 0.f, 0.f};

  #pragma unroll
  for (int ks = 0; ks < 64; ks += 32) {
    bf16x8 ah[4], al[4], bh[2], bl[2];
    #pragma unroll
    for (int r = 0; r < 4; r++) {
      int o = (waveRow + r * 16 + frow) * LD + ks + fk;
      ah[r] = *reinterpret_cast<const bf16x8*>(&sAh[o]);
      al[r] = *reinterpret_cast<const bf16x8*>(&sAl[o]);
    }
    #pragma unroll
    for (int c = 0; c < 2; c++) {
      int o = (waveCol + c * 16 + frow) * LD + ks + fk;
      bh[c] = *reinterpret_cast<const bf16x8*>(&sBh[o]);
      bl[c] = *reinterpret_cast<const bf16x8*>(&sBl[o]);
    }
    #pragma unroll
    for (int r = 0; r < 4; r++)
      #pragma unroll
      for (int c = 0; c < 2; c++) {
        acc[r][c] = __builtin_amdgcn_mfma_f32_16x16x32_bf16(ah[r], bh[c], acc[r][c], 0, 0, 0);
        acc[r][c] = __builtin_amdgcn_mfma_f32_16x16x32_bf16(ah[r], bl[c], acc[r][c], 0, 0, 0);
        acc[r][c] = __builtin_amdgcn_mfma_f32_16x16x32_bf16(al[r], bh[c], acc[r][c], 0, 0, 0);
      }
  }

  bf16* dst = z ? phik : phiq;
  #pragma unroll
  for (int r = 0; r < 4; r++)
    #pragma unroll
    for (int c = 0; c < 2; c++)
      #pragma unroll
      for (int reg = 0; reg < 4; reg++) {
        int row = waveRow + r * 16 + (lane >> 4) * 4 + reg;
        int col = waveCol + c * 16 + (lane & 15);
        float norm = 0.5f * (sPart[row][0] + sPart[row][1]);
        float v = __expf(fminf(acc[r][c][reg] - norm, 80.f)) * 0.125f;
        dst[((size_t)h * N_TOK + n0 + row) * FM + col] = __float2bfloat16(v);
      }
}

// MFMA chunk sums: ckv_t[h][c][d][m] = sum_j v[j][d]*phik[j][m]; ck = col sums of phik.
__global__ __launch_bounds__(256) void chunk_sum(
    const bf16* __restrict__ phik, const bf16* __restrict__ vf,
    float* __restrict__ ckv_t, float* __restrict__ ck)
{
  constexpr int LD = 72;
  __shared__ short sVt[64 * LD], sPkt[64 * LD];
  __shared__ float sCp[64][4];
  const int c = blockIdx.x, h = blockIdx.y;
  const int tid = threadIdx.x, lane = tid & 63, wv = tid >> 6;

  // stage transposed: sVt[d][j], sPkt[m][j]
  {
    int j = tid >> 2, g = tid & 3;
    const bf16* vs = vf + (size_t)(c * CS + j) * DIMM + h * HD + g * 16;
    uint4 v0 = *reinterpret_cast<const uint4*>(vs);
    uint4 v1 = *reinterpret_cast<const uint4*>(vs + 8);
    const unsigned short* pv = (const unsigned short*)&v0;
    #pragma unroll
    for (int e = 0; e < 8; e++) sVt[(g * 16 + e) * LD + j] = (short)pv[e];
    pv = (const unsigned short*)&v1;
    #pragma unroll
    for (int e = 0; e < 8; e++) sVt[(g * 16 + 8 + e) * LD + j] = (short)pv[e];

    const bf16* ks = phik + ((size_t)h * N_TOK + c * CS + j) * FM + g * 16;
    uint4 k0 = *reinterpret_cast<const uint4*>(ks);
    uint4 k1 = *reinterpret_cast<const uint4*>(ks + 8);
    pv = (const unsigned short*)&k0;
    #pragma unroll
    for (int e = 0; e < 8; e++) sPkt[(g * 16 + e) * LD + j] = (short)pv[e];
    pv = (const unsigned short*)&k1;
    #pragma unroll
    for (int e = 0; e < 8; e++) sPkt[(g * 16 + 8 + e) * LD + j] = (short)pv[e];
  }
  __syncthreads();

  const int frow = lane & 15, fk = (lane >> 4) * 8;
  const int rowW = wv * 16;

  f32x4 acc[4];
  #pragma unroll
  for (int mt = 0; mt < 4; mt++) acc[mt] = (f32x4){0.f, 0.f, 0.f, 0.f};
  #pragma unroll
  for (int ks = 0; ks < 64; ks += 32) {
    bf16x8 a = *reinterpret_cast<const bf16x8*>(&sVt[(rowW + frow) * LD + ks + fk]);
    #pragma unroll
    for (int mt = 0; mt < 4; mt++) {
      bf16x8 b = *reinterpret_cast<const bf16x8*>(&sPkt[(mt * 16 + frow) * LD + ks + fk]);
      acc[mt] = __builtin_amdgcn_mfma_f32_16x16x32_bf16(a, b, acc[mt], 0, 0, 0);
    }
  }

  // ck partials: thread t sums 16 j's of phik col m
  {
    int m = tid >> 2, q = tid & 3;
    float s = 0.f;
    #pragma unroll
    for (int e = 0; e < 16; e++)
      s += b2f(*reinterpret_cast<bf16*>(&sPkt[m * LD + q * 16 + e]));
    sCp[m][q] = s;
  }
  __syncthreads();
  if (tid < 64)
    ck[((size_t)h * NC + c) * FM + tid] = sCp[tid][0] + sCp[tid][1] + sCp[tid][2] + sCp[tid][3];

  float* dst = ckv_t + ((size_t)h * NC + c) * 4096;
  #pragma unroll
  for (int mt = 0; mt < 4; mt++)
    #pragma unroll
    for (int reg = 0; reg < 4; reg++) {
      int gd = rowW + (lane >> 4) * 4 + reg;
      int gm = mt * 16 + (lane & 15);
      dst[gd * 64 + gm] = acc[mt][reg];
    }
}

// Register-blocked exclusive prefix over chunks (layout-agnostic).
__global__ __launch_bounds__(256) void prefix_chunks(
    float* __restrict__ ckv, float* __restrict__ ck)
{
  const int h = blockIdx.x, g = blockIdx.y;
  const int cell = g * 256 + threadIdx.x;
  const size_t base = (size_t)h * NC * 4096 + cell;
  float v[NC];
  #pragma unroll
  for (int c = 0; c < NC; c++) v[c] = ckv[base + (size_t)c * 4096];
  float run = 0.f;
  #pragma unroll
  for (int c = 0; c < NC; c++) { float t = v[c]; ckv[base + (size_t)c * 4096] = run; run += t; }
  if (g == 0 && threadIdx.x < 64) {
    const size_t b2 = (size_t)h * NC * FM + threadIdx.x;
    float u[NC];
    #pragma unroll
    for (int c = 0; c < NC; c++) u[c] = ck[b2 + (size_t)c * FM];
    float r2 = 0.f;
    #pragma unroll
    for (int c = 0; c < NC; c++) { float t = u[c]; ck[b2 + (size_t)c * FM] = r2; r2 += t; }
  }
}

// MFMA causal chunk attention.
__global__ __launch_bounds__(256) void attn_chunk(
    const bf16* __restrict__ phiq, const bf16* __restrict__ phik,
    const bf16* __restrict__ vf, const float* __restrict__ ckv_t,
    const float* __restrict__ ck, bf16* __restrict__ attn_out)
{
  constexpr int LD = 72;
  __shared__ short sPq[64 * LD];
  __shared__ short sPk[64 * LD];   // phik rows; reused as masked A_hi
  __shared__ short sAl[64 * LD];   // masked A_lo
  __shared__ short sVt[64 * LD];
  __shared__ short sSh[64 * LD];
  __shared__ short sSl[64 * LD];
  __shared__ float sKc[64];
  __shared__ float sDp[64][4];
  __shared__ float sDen[64];

  const int c = blockIdx.x, h = blockIdx.y;
  const int tid = threadIdx.x, lane = tid & 63, wv = tid >> 6;

  // --- stage ---
  {
    int r = tid >> 2, g = tid & 3;
    const size_t gb = ((size_t)h * N_TOK + c * CS + r) * FM + g * 16;
    uint4 q0 = *reinterpret_cast<const uint4*>(phiq + gb);
    uint4 q1 = *reinterpret_cast<const uint4*>(phiq + gb + 8);
    uint4 k0 = *reinterpret_cast<const uint4*>(phik + gb);
    uint4 k1 = *reinterpret_cast<const uint4*>(phik + gb + 8);
    int o = r * LD + g * 16;
    *reinterpret_cast<uint4*>(&sPq[o]) = q0; *reinterpret_cast<uint4*>(&sPq[o + 8]) = q1;
    *reinterpret_cast<uint4*>(&sPk[o]) = k0; *reinterpret_cast<uint4*>(&sPk[o + 8]) = k1;
  }
  {
    int j = tid >> 2, g = tid & 3;
    const bf16* vs = vf + (size_t)(c * CS + j) * DIMM + h * HD + g * 16;
    uint4 v0 = *reinterpret_cast<const uint4*>(vs);
    uint4 v1 = *reinterpret_cast<const uint4*>(vs + 8);
    const unsigned short* pv = (const unsigned short*)&v0;
    #pragma unroll
    for (int e = 0; e < 8; e++) sVt[(g * 16 + e) * LD + j] = (short)pv[e];
    pv = (const unsigned short*)&v1;
    #pragma unroll
    for (int e = 0; e < 8; e++) sVt[(g * 16 + 8 + e) * LD + j] = (short)pv[e];
  }
  {
    int d = tid >> 2, mg = tid & 3;
    const float* src = ckv_t + ((size_t)h * NC + c) * 4096 + d * 64 + mg * 16;
    int o = d * LD + mg * 16;
    #pragma unroll
    for (int e4 = 0; e4 < 4; e4++) {
      float4 v = *reinterpret_cast<const float4*>(src + e4 * 4);
      uint2 ph, pl;
      split_pack_bf(v, ph, pl);
      *reinterpret_cast<uint2*>(&sSh[o + e4 * 4]) = ph;
      *reinterpret_cast<uint2*>(&sSl[o + e4 * 4]) = pl;
    }
  }
  if (tid < 64) sKc[tid] = ck[((size_t)h * NC + c) * FM + tid];
  __syncthreads();

  const int frow = lane & 15, fk = (lane >> 4) * 8;
  const int rowW = wv * 16;

  // --- phase 1: A = phiq . phik^T, rows rowW..rowW+15 ---
  f32x4 accA[4];
  #pragma unroll
  for (int ct = 0; ct < 4; ct++) accA[ct] = (f32x4){0.f, 0.f, 0.f, 0.f};
  #pragma unroll
  for (int ks = 0; ks < 64; ks += 32) {
    bf16x8 a = *reinterpret_cast<const bf16x8*>(&sPq[(rowW + frow) * LD + ks + fk]);
    #pragma unroll
    for (int ct = 0; ct < 4; ct++) {
      bf16x8 b = *reinterpret_cast<const bf16x8*>(&sPk[(ct * 16 + frow) * LD + ks + fk]);
      accA[ct] = __builtin_amdgcn_mfma_f32_16x16x32_bf16(a, b, accA[ct], 0, 0, 0);
    }
  }
  __syncthreads();   // all reads of sPk (phik) done

  // mask + bf16 hi/lo split into sPk (Ah) / sAl
  #pragma unroll
  for (int ct = 0; ct < 4; ct++)
    #pragma unroll
    for (int reg = 0; reg < 4; reg++) {
      int gi = rowW + (lane >> 4) * 4 + reg;
      int gj = ct * 16 + (lane & 15);
      float av = (gj <= gi) ? accA[ct][reg] : 0.f;
      bf16 hb = __float2bfloat16(av);
      sPk[gi * LD + gj] = *reinterpret_cast<short*>(&hb);
      unsigned short lu = f2bfu(av - b2f(hb));
      sAl[gi * LD + gj] = (short)lu;
    }
  __syncthreads();

  // --- den partials (256 threads) ---
  {
    int i = tid >> 2, q = tid & 3;
    float p = 0.f;
    #pragma unroll
    for (int e = 0; e < 16; e++) {
      int m = q * 16 + e;
      p += b2f(*reinterpret_cast<bf16*>(&sPq[i * LD + m])) * sKc[m];
      p += b2f(*reinterpret_cast<bf16*>(&sPk[i * LD + m]))
         + b2f(*reinterpret_cast<bf16*>(&sAl[i * LD + m]));
    }
    sDp[i][q] = p;
  }

  // --- phase 3: out = (Ah+Al).V + phiq.(Sh+Sl) ---
  f32x4 accO[4];
  #pragma unroll
  for (int dt = 0; dt < 4; dt++) accO[dt] = (f32x4){0.f, 0.f, 0.f, 0.f};
  #pragma unroll
  for (int ks = 0; ks < 64; ks += 32) {
    bf16x8 ah = *reinterpret_cast<const bf16x8*>(&sPk[(rowW + frow) * LD + ks + fk]);
    bf16x8 al = *reinterpret_cast<const bf16x8*>(&sAl[(rowW + frow) * LD + ks + fk]);
    bf16x8 aq = *reinterpret_cast<const bf16x8*>(&sPq[(rowW + frow) * LD + ks + fk]);
    #pragma unroll
    for (int dt = 0; dt < 4; dt++) {
      bf16x8 bv = *reinterpret_cast<const bf16x8*>(&sVt[(dt * 16 + frow) * LD + ks + fk]);
      bf16x8 bh = *reinterpret_cast<const bf16x8*>(&sSh[(dt * 16 + frow) * LD + ks + fk]);
      bf16x8 bl = *reinterpret_cast<const bf16x8*>(&sSl[(dt * 16 + frow) * LD + ks + fk]);
      accO[dt] = __builtin_amdgcn_mfma_f32_16x16x32_bf16(ah, bv, accO[dt], 0, 0, 0);
      accO[dt] = __builtin_amdgcn_mfma_f32_16x16x32_bf16(al, bv, accO[dt], 0, 0, 0);
      accO[dt] = __builtin_amdgcn_mfma_f32_16x16x32_bf16(aq, bh, accO[dt], 0, 0, 0);
      accO[dt] = __builtin_amdgcn_mfma_f32_16x16x32_bf16(aq, bl, accO[dt], 0, 0, 0);
    }
  }
  __syncthreads();
  if (tid < 64) {
    float den = sDp[tid][0] + sDp[tid][1] + sDp[tid][2] + sDp[tid][3];
    sDen[tid] = 1.f / (den + 1e-6f);
  }
  __syncthreads();

  #pragma unroll
  for (int dt = 0; dt < 4; dt++)
    #pragma unroll
    for (int reg = 0; reg < 4; reg++) {
      int gi = rowW + (lane >> 4) * 4 + reg;
      int gd = dt * 16 + (lane & 15);
      float v = accO[dt][reg] * sDen[gi];
      attn_out[(size_t)(c * CS + gi) * DIMM + h * HD + gd] = __float2bfloat16(v);
    }
}

extern "C" void kernel_launch(void* const* d_in, const int* in_sizes, int n_in,
                              void* d_out, int out_size, void* d_ws, size_t ws_size,
                              hipStream_t stream) {
  (void)in_sizes; (void)n_in; (void)out_size; (void)ws_size;
  const float* x     = (const float*)d_in[0];
  const float* omega = (const float*)d_in[1];
  const float* wq    = (const float*)d_in[2];
  const float* wk    = (const float*)d_in[3];
  const float* wv    = (const float*)d_in[4];
  const float* wo    = (const float*)d_in[5];
  const float* bo    = (const float*)d_in[6];
  float* out = (float*)d_out;

  char* w = (char*)d_ws;
  _Float16* x16   = (_Float16*)(w);                  // 4 MB  [later: attn bf16 alias]
  _Float16* w16   = (_Float16*)(w + (4u  << 20));    // 6 MB
  bf16*     wo_bf = (bf16*)   (w + (10u << 20));     // 2 MB
  _Float16* qk    = (_Float16*)(w + (12u << 20));    // 8 MB
  bf16*     vbf   = (bf16*)   (w + (20u << 20));     // 4 MB
  bf16*     phiq  = (bf16*)   (w + (24u << 20));     // 4 MB
  bf16*     phik  = (bf16*)   (w + (28u << 20));     // 4 MB
  float*    ckv   = (float*)  (w + (32u << 20));     // 8 MB (transposed [d][m])
  float*    ck    = (float*)  (w + (40u << 20));     // 128 KB
  bf16*     attnb = (bf16*)x16;

  cvt_all<<<6144, 256, 0, stream>>>((const float4*)x, (const float4*)wq,
                                    (const float4*)wk, (const float4*)wv,
                                    (const float4*)wo,
                                    x16, w16, wo_bf);

  gemm_qkv_f16<<<dim3(24, 16), 256, 0, stream>>>(x16, w16, qk, vbf);

  phi_mfma<<<dim3(N_TOK / 128, NH, 2), 256, 0, stream>>>(qk, omega, phiq, phik);

  chunk_sum<<<dim3(NC, NH), 256, 0, stream>>>(phik, vbf, ckv, ck);
  prefix_chunks<<<dim3(NH, 16), 256, 0, stream>>>(ckv, ck);
  attn_chunk<<<dim3(NC, NH), 256, 0, stream>>>(phiq, phik, vbf, ckv, ck, attnb);

  gemm_bf16_out<<<dim3(8, 32), 256, 0, stream>>>(attnb, wo_bf, bo, out);
}

// Round 10
// 143.270 us; speedup vs baseline: 1.4611x; 1.0586x over previous
//
#include <hip/hip_runtime.h>
#include <hip/hip_bf16.h>

typedef __hip_bfloat16 bf16;
typedef __attribute__((ext_vector_type(8))) short bf16x8;
typedef __attribute__((ext_vector_type(8))) _Float16 f16x8;
typedef __attribute__((ext_vector_type(4))) float f32x4;

constexpr int N_TOK = 2048;
constexpr int DIMM  = 1024;
constexpr int NH    = 16;
constexpr int HD    = 64;
constexpr int FM    = 64;
constexpr int NC    = 32;
constexpr int CS    = 64;

__device__ __forceinline__ float b2f(bf16 v) { return __bfloat162float(v); }
__device__ __forceinline__ unsigned short f2bfu(float v) {
  bf16 h = __float2bfloat16(v);
  return *reinterpret_cast<unsigned short*>(&h);
}
__device__ __forceinline__ unsigned short f2hu(float v) {
  _Float16 h = (_Float16)v;
  return *reinterpret_cast<unsigned short*>(&h);
}

__device__ __forceinline__ void gl_lds16(const void* g, short* l) {
  __builtin_amdgcn_global_load_lds(
      (const __attribute__((address_space(1))) void*)g,
      (__attribute__((address_space(3))) void*)l, 16, 0, 0);
}

__device__ __forceinline__ void split_pack_bf(const float4 v, uint2& ph, uint2& pl) {
  float f[4] = {v.x, v.y, v.z, v.w};
  unsigned short h[4], l[4];
  #pragma unroll
  for (int j = 0; j < 4; j++) {
    bf16 hb = __float2bfloat16(f[j]);
    h[j] = *reinterpret_cast<unsigned short*>(&hb);
    l[j] = f2bfu(f[j] - b2f(hb));
  }
  ph.x = (unsigned)h[0] | ((unsigned)h[1] << 16);
  ph.y = (unsigned)h[2] | ((unsigned)h[3] << 16);
  pl.x = (unsigned)l[0] | ((unsigned)l[1] << 16);
  pl.y = (unsigned)l[2] | ((unsigned)l[3] << 16);
}

// Fused conversions: x -> fp16; wq|wk|wv -> fp16 [3072][1024]; wo -> bf16.
__global__ __launch_bounds__(256) void cvt_all(
    const float4* __restrict__ x, const float4* __restrict__ wq,
    const float4* __restrict__ wk, const float4* __restrict__ wv,
    const float4* __restrict__ wo,
    _Float16* __restrict__ x16, _Float16* __restrict__ w16,
    bf16* __restrict__ wo_bf)
{
  int i = blockIdx.x * 256 + threadIdx.x;   // < 1572864
  if (i < 524288) {
    float4 v = x[i];
    uint2 p = { (unsigned)f2hu(v.x) | ((unsigned)f2hu(v.y) << 16),
                (unsigned)f2hu(v.z) | ((unsigned)f2hu(v.w) << 16) };
    reinterpret_cast<uint2*>(x16)[i] = p;
  } else if (i < 1310720) {
    int j = i - 524288;
    const float4* src = (j < 262144) ? wq : (j < 524288) ? wk : wv;
    int jj = (j < 262144) ? j : (j < 524288) ? j - 262144 : j - 524288;
    float4 v = src[jj];
    uint2 p = { (unsigned)f2hu(v.x) | ((unsigned)f2hu(v.y) << 16),
                (unsigned)f2hu(v.z) | ((unsigned)f2hu(v.w) << 16) };
    reinterpret_cast<uint2*>(w16)[j] = p;
  } else {
    int j = i - 1310720;
    float4 v = wo[j];
    uint2 p = { (unsigned)f2bfu(v.x) | ((unsigned)f2bfu(v.y) << 16),
                (unsigned)f2bfu(v.z) | ((unsigned)f2bfu(v.w) << 16) };
    reinterpret_cast<uint2*>(wo_bf)[j] = p;
  }
}

// QKV projection: single fp16 MFMA product. Block 128x128, BK=32, dbuf 32 KB.
// 512 threads = 8 waves (2 row x 4 col, wave tile 64x32) -> 12 waves/CU at grid 384.
__global__ __launch_bounds__(512) void gemm_qkv_f16(
    const _Float16* __restrict__ A16, const _Float16* __restrict__ B16,
    _Float16* __restrict__ Cq, bf16* __restrict__ Cv)
{
  constexpr int K = 1024;
  __shared__ short sA[2][4096], sB[2][4096];
  const int tid = threadIdx.x, lane = tid & 63, wv = tid >> 6;   // wv 0..7
  const int colBase = blockIdx.x * 128, rowBase = blockIdx.y * 128;
  const int waveRow = (wv >> 2) * 64, waveCol = (wv & 3) * 32;
  const int stR = tid >> 2, stK = (tid & 3) * 8;                 // 128 rows x 32 k

  const _Float16* gA = A16 + (size_t)(rowBase + stR) * K + stK;
  const _Float16* gB = B16 + (size_t)(colBase + stR) * K + stK;
  const int ldsOff = wv * 512;   // each wave stages one 512-elem chunk

  f32x4 acc[4][2];
  #pragma unroll
  for (int r = 0; r < 4; r++)
    #pragma unroll
    for (int c = 0; c < 2; c++) acc[r][c] = (f32x4){0.f, 0.f, 0.f, 0.f};

  const int frow = lane & 15, fk = (lane >> 4) * 8;
  const int nIter = K / 32;

  gl_lds16(gA, &sA[0][ldsOff]);
  gl_lds16(gB, &sB[0][ldsOff]);

  int buf = 0;
  for (int it = 0; it < nIter; it++) {
    __syncthreads();
    if (it + 1 < nIter) {
      const size_t kb = (size_t)(it + 1) * 32;
      const int nb = buf ^ 1;
      gl_lds16(gA + kb, &sA[nb][ldsOff]);
      gl_lds16(gB + kb, &sB[nb][ldsOff]);
    }
    f16x8 a[4], b[2];
    #pragma unroll
    for (int r = 0; r < 4; r++)
      a[r] = *reinterpret_cast<const f16x8*>(&sA[buf][(waveRow + r * 16 + frow) * 32 + fk]);
    #pragma unroll
    for (int c = 0; c < 2; c++)
      b[c] = *reinterpret_cast<const f16x8*>(&sB[buf][(waveCol + c * 16 + frow) * 32 + fk]);
    #pragma unroll
    for (int r = 0; r < 4; r++)
      #pragma unroll
      for (int c = 0; c < 2; c++)
        acc[r][c] = __builtin_amdgcn_mfma_f32_16x16x32_f16(a[r], b[c], acc[r][c], 0, 0, 0);
    buf ^= 1;
  }

  #pragma unroll
  for (int r = 0; r < 4; r++)
    #pragma unroll
    for (int c = 0; c < 2; c++)
      #pragma unroll
      for (int reg = 0; reg < 4; reg++) {
        int row = rowBase + waveRow + r * 16 + (lane >> 4) * 4 + reg;
        int col = colBase + waveCol + c * 16 + (lane & 15);
        float v = acc[r][c][reg];
        if (col < 2048) Cq[(size_t)row * 2048 + col] = (_Float16)v;
        else            Cv[(size_t)row * 1024 + (col - 2048)] = __float2bfloat16(v);
      }
}

// Output projection: bf16 NT GEMM + bias, fp32 out. Block 64x128, 512 threads
// = 8 waves (2x4, wave tile 32x32), dbuf LDS 24 KB. Grid (8,32)=256 blocks.
__global__ __launch_bounds__(512) void gemm_bf16_out(
    const bf16* __restrict__ A, const bf16* __restrict__ B,
    const float* __restrict__ bias, float* __restrict__ C)
{
  constexpr int K = 1024;
  __shared__ short sA[2][2048], sB[2][4096];
  const int tid = threadIdx.x, lane = tid & 63, wv = tid >> 6;
  const int rowBase = blockIdx.y * 64, colBase = blockIdx.x * 128;
  const int waveRow = (wv >> 2) * 32, waveCol = (wv & 3) * 32;
  const int stR = tid >> 2, stK = (tid & 3) * 8;
  const bf16* gA = A + (size_t)(rowBase + stR) * K + stK;   // valid for wv<4 only
  const bf16* gB = B + (size_t)(colBase + stR) * K + stK;
  const int ldsOff = wv * 512;

  f32x4 acc[2][2];
  #pragma unroll
  for (int r = 0; r < 2; r++)
    #pragma unroll
    for (int c = 0; c < 2; c++) acc[r][c] = (f32x4){0.f, 0.f, 0.f, 0.f};

  const int frow = lane & 15, fk = (lane >> 4) * 8;
  const int nIter = K / 32;

  if (wv < 4) gl_lds16(gA, &sA[0][ldsOff]);
  gl_lds16(gB, &sB[0][ldsOff]);

  int buf = 0;
  for (int it = 0; it < nIter; it++) {
    __syncthreads();
    if (it + 1 < nIter) {
      const size_t kb = (size_t)(it + 1) * 32;
      const int nb = buf ^ 1;
      if (wv < 4) gl_lds16(gA + kb, &sA[nb][ldsOff]);
      gl_lds16(gB + kb, &sB[nb][ldsOff]);
    }
    bf16x8 a[2], b[2];
    #pragma unroll
    for (int r = 0; r < 2; r++)
      a[r] = *reinterpret_cast<const bf16x8*>(&sA[buf][(waveRow + r * 16 + frow) * 32 + fk]);
    #pragma unroll
    for (int c = 0; c < 2; c++)
      b[c] = *reinterpret_cast<const bf16x8*>(&sB[buf][(waveCol + c * 16 + frow) * 32 + fk]);
    #pragma unroll
    for (int r = 0; r < 2; r++)
      #pragma unroll
      for (int c = 0; c < 2; c++)
        acc[r][c] = __builtin_amdgcn_mfma_f32_16x16x32_bf16(a[r], b[c], acc[r][c], 0, 0, 0);
    buf ^= 1;
  }

  #pragma unroll
  for (int r = 0; r < 2; r++)
    #pragma unroll
    for (int c = 0; c < 2; c++)
      #pragma unroll
      for (int reg = 0; reg < 4; reg++) {
        int row = rowBase + waveRow + r * 16 + (lane >> 4) * 4 + reg;
        int col = colBase + waveCol + c * 16 + (lane & 15);
        C[(size_t)row * 1024 + col] = acc[r][c][reg] + bias[col];
      }
}

// MFMA phi from fp16 qk: phi = exp(q.omega - 0.5||q||^2)/8, bf16 out [h][n][m].
__global__ __launch_bounds__(256) void phi_mfma(
    const _Float16* __restrict__ qk, const float* __restrict__ omega,
    bf16* __restrict__ phiq, bf16* __restrict__ phik)
{
  constexpr int LD = 72;
  __shared__ short sAh[128 * LD], sAl[128 * LD];
  __shared__ short sBh[64 * LD],  sBl[64 * LD];
  __shared__ float sPart[128][2];

  const int tid = threadIdx.x, lane = tid & 63, wv = tid >> 6;
  const int n0 = blockIdx.x * 128, h = blockIdx.y, z = blockIdx.z;
  const int colOff = z * 1024 + h * HD;

  {
    const int r = tid >> 1, half = tid & 1;
    const _Float16* src = qk + (size_t)(n0 + r) * 2048 + colOff + half * 32;
    float ssq = 0.f;
    #pragma unroll
    for (int j8 = 0; j8 < 4; j8++) {
      uint4 raw = reinterpret_cast<const uint4*>(src)[j8];
      const unsigned short* hs = reinterpret_cast<const unsigned short*>(&raw);
      unsigned short hh[8], ll[8];
      #pragma unroll
      for (int j = 0; j < 8; j++) {
        _Float16 hv;
        *reinterpret_cast<unsigned short*>(&hv) = hs[j];
        float f = (float)hv;
        ssq += f * f;
        bf16 hb = __float2bfloat16(f);
        hh[j] = *reinterpret_cast<unsigned short*>(&hb);
        ll[j] = f2bfu(f - b2f(hb));
      }
      int o = r * LD + half * 32 + j8 * 8;
      uint4 ph = { (unsigned)hh[0] | ((unsigned)hh[1] << 16),
                   (unsigned)hh[2] | ((unsigned)hh[3] << 16),
                   (unsigned)hh[4] | ((unsigned)hh[5] << 16),
                   (unsigned)hh[6] | ((unsigned)hh[7] << 16) };
      uint4 pl = { (unsigned)ll[0] | ((unsigned)ll[1] << 16),
                   (unsigned)ll[2] | ((unsigned)ll[3] << 16),
                   (unsigned)ll[4] | ((unsigned)ll[5] << 16),
                   (unsigned)ll[6] | ((unsigned)ll[7] << 16) };
      *reinterpret_cast<uint4*>(&sAh[o]) = ph;
      *reinterpret_cast<uint4*>(&sAl[o]) = pl;
    }
    sPart[r][half] = ssq;
  }
  {
    const int r = tid >> 2, q4 = tid & 3;
    const float* src = omega + (size_t)r * FM + q4 * 16;
    #pragma unroll
    for (int j4 = 0; j4 < 4; j4++) {
      float4 v = reinterpret_cast<const float4*>(src)[j4];
      uint2 ph, pl;
      split_pack_bf(v, ph, pl);
      int o = r * LD + q4 * 16 + j4 * 4;
      *reinterpret_cast<uint2*>(&sBh[o]) = ph;
      *reinterpret_cast<uint2*>(&sBl[o]) = pl;
    }
  }
  __syncthreads();

  const int waveRow = (wv >> 1) * 64, waveCol = (wv & 1) * 32;
  const int frow = lane & 15, fk = (lane >> 4) * 8;

  f32x4 acc[4][2];
  #pragma unroll
  for (int r = 0; r < 4; r++)
    #pragma unroll
    for (int c = 0; c < 2; c++) acc[r][c] = (f32x4){0.f, 0.f, 0.f, 0.f};

  #pragma unroll
  for (int ks = 0; ks < 64; ks += 32) {
    bf16x8 ah[4], al[4], bh[2], bl[2];
    #pragma unroll
    for (int r = 0; r < 4; r++) {
      int o = (waveRow + r * 16 + frow) * LD + ks + fk;
      ah[r] = *reinterpret_cast<const bf16x8*>(&sAh[o]);
      al[r] = *reinterpret_cast<const bf16x8*>(&sAl[o]);
    }
    #pragma unroll
    for (int c = 0; c < 2; c++) {
      int o = (waveCol + c * 16 + frow) * LD + ks + fk;
      bh[c] = *reinterpret_cast<const bf16x8*>(&sBh[o]);
      bl[c] = *reinterpret_cast<const bf16x8*>(&sBl[o]);
    }
    #pragma unroll
    for (int r = 0; r < 4; r++)
      #pragma unroll
      for (int c = 0; c < 2; c++) {
        acc[r][c] = __builtin_amdgcn_mfma_f32_16x16x32_bf16(ah[r], bh[c], acc[r][c], 0, 0, 0);
        acc[r][c] = __builtin_amdgcn_mfma_f32_16x16x32_bf16(ah[r], bl[c], acc[r][c], 0, 0, 0);
        acc[r][c] = __builtin_amdgcn_mfma_f32_16x16x32_bf16(al[r], bh[c], acc[r][c], 0, 0, 0);
      }
  }

  bf16* dst = z ? phik : phiq;
  #pragma unroll
  for (int r = 0; r < 4; r++)
    #pragma unroll
    for (int c = 0; c < 2; c++)
      #pragma unroll
      for (int reg = 0; reg < 4; reg++) {
        int row = waveRow + r * 16 + (lane >> 4) * 4 + reg;
        int col = waveCol + c * 16 + (lane & 15);
        float norm = 0.5f * (sPart[row][0] + sPart[row][1]);
        float v = __expf(fminf(acc[r][c][reg] - norm, 80.f)) * 0.125f;
        dst[((size_t)h * N_TOK + n0 + row) * FM + col] = __float2bfloat16(v);
      }
}

// MFMA chunk sums: ckv_t[h][c][d][m] = sum_j v[j][d]*phik[j][m]; ck = col sums of phik.
__global__ __launch_bounds__(256) void chunk_sum(
    const bf16* __restrict__ phik, const bf16* __restrict__ vf,
    float* __restrict__ ckv_t, float* __restrict__ ck)
{
  constexpr int LD = 72;
  __shared__ short sVt[64 * LD], sPkt[64 * LD];
  __shared__ float sCp[64][4];
  const int c = blockIdx.x, h = blockIdx.y;
  const int tid = threadIdx.x, lane = tid & 63, wv = tid >> 6;

  {
    int j = tid >> 2, g = tid & 3;
    const bf16* vs = vf + (size_t)(c * CS + j) * DIMM + h * HD + g * 16;
    uint4 v0 = *reinterpret_cast<const uint4*>(vs);
    uint4 v1 = *reinterpret_cast<const uint4*>(vs + 8);
    const unsigned short* pv = (const unsigned short*)&v0;
    #pragma unroll
    for (int e = 0; e < 8; e++) sVt[(g * 16 + e) * LD + j] = (short)pv[e];
    pv = (const unsigned short*)&v1;
    #pragma unroll
    for (int e = 0; e < 8; e++) sVt[(g * 16 + 8 + e) * LD + j] = (short)pv[e];

    const bf16* ks = phik + ((size_t)h * N_TOK + c * CS + j) * FM + g * 16;
    uint4 k0 = *reinterpret_cast<const uint4*>(ks);
    uint4 k1 = *reinterpret_cast<const uint4*>(ks + 8);
    pv = (const unsigned short*)&k0;
    #pragma unroll
    for (int e = 0; e < 8; e++) sPkt[(g * 16 + e) * LD + j] = (short)pv[e];
    pv = (const unsigned short*)&k1;
    #pragma unroll
    for (int e = 0; e < 8; e++) sPkt[(g * 16 + 8 + e) * LD + j] = (short)pv[e];
  }
  __syncthreads();

  const int frow = lane & 15, fk = (lane >> 4) * 8;
  const int rowW = wv * 16;

  f32x4 acc[4];
  #pragma unroll
  for (int mt = 0; mt < 4; mt++) acc[mt] = (f32x4){0.f, 0.f, 0.f, 0.f};
  #pragma unroll
  for (int ks = 0; ks < 64; ks += 32) {
    bf16x8 a = *reinterpret_cast<const bf16x8*>(&sVt[(rowW + frow) * LD + ks + fk]);
    #pragma unroll
    for (int mt = 0; mt < 4; mt++) {
      bf16x8 b = *reinterpret_cast<const bf16x8*>(&sPkt[(mt * 16 + frow) * LD + ks + fk]);
      acc[mt] = __builtin_amdgcn_mfma_f32_16x16x32_bf16(a, b, acc[mt], 0, 0, 0);
    }
  }

  {
    int m = tid >> 2, q = tid & 3;
    float s = 0.f;
    #pragma unroll
    for (int e = 0; e < 16; e++)
      s += b2f(*reinterpret_cast<bf16*>(&sPkt[m * LD + q * 16 + e]));
    sCp[m][q] = s;
  }
  __syncthreads();
  if (tid < 64)
    ck[((size_t)h * NC + c) * FM + tid] = sCp[tid][0] + sCp[tid][1] + sCp[tid][2] + sCp[tid][3];

  float* dst = ckv_t + ((size_t)h * NC + c) * 4096;
  #pragma unroll
  for (int mt = 0; mt < 4; mt++)
    #pragma unroll
    for (int reg = 0; reg < 4; reg++) {
      int gd = rowW + (lane >> 4) * 4 + reg;
      int gm = mt * 16 + (lane & 15);
      dst[gd * 64 + gm] = acc[mt][reg];
    }
}

// Register-blocked exclusive prefix over chunks (layout-agnostic).
__global__ __launch_bounds__(256) void prefix_chunks(
    float* __restrict__ ckv, float* __restrict__ ck)
{
  const int h = blockIdx.x, g = blockIdx.y;
  const int cell = g * 256 + threadIdx.x;
  const size_t base = (size_t)h * NC * 4096 + cell;
  float v[NC];
  #pragma unroll
  for (int c = 0; c < NC; c++) v[c] = ckv[base + (size_t)c * 4096];
  float run = 0.f;
  #pragma unroll
  for (int c = 0; c < NC; c++) { float t = v[c]; ckv[base + (size_t)c * 4096] = run; run += t; }
  if (g == 0 && threadIdx.x < 64) {
    const size_t b2 = (size_t)h * NC * FM + threadIdx.x;
    float u[NC];
    #pragma unroll
    for (int c = 0; c < NC; c++) u[c] = ck[b2 + (size_t)c * FM];
    float r2 = 0.f;
    #pragma unroll
    for (int c = 0; c < NC; c++) { float t = u[c]; ck[b2 + (size_t)c * FM] = r2; r2 += t; }
  }
}

// MFMA causal chunk attention.
__global__ __launch_bounds__(256) void attn_chunk(
    const bf16* __restrict__ phiq, const bf16* __restrict__ phik,
    const bf16* __restrict__ vf, const float* __restrict__ ckv_t,
    const float* __restrict__ ck, bf16* __restrict__ attn_out)
{
  constexpr int LD = 72;
  __shared__ short sPq[64 * LD];
  __shared__ short sPk[64 * LD];
  __shared__ short sAl[64 * LD];
  __shared__ short sVt[64 * LD];
  __shared__ short sSh[64 * LD];
  __shared__ short sSl[64 * LD];
  __shared__ float sKc[64];
  __shared__ float sDp[64][4];
  __shared__ float sDen[64];

  const int c = blockIdx.x, h = blockIdx.y;
  const int tid = threadIdx.x, lane = tid & 63, wv = tid >> 6;

  {
    int r = tid >> 2, g = tid & 3;
    const size_t gb = ((size_t)h * N_TOK + c * CS + r) * FM + g * 16;
    uint4 q0 = *reinterpret_cast<const uint4*>(phiq + gb);
    uint4 q1 = *reinterpret_cast<const uint4*>(phiq + gb + 8);
    uint4 k0 = *reinterpret_cast<const uint4*>(phik + gb);
    uint4 k1 = *reinterpret_cast<const uint4*>(phik + gb + 8);
    int o = r * LD + g * 16;
    *reinterpret_cast<uint4*>(&sPq[o]) = q0; *reinterpret_cast<uint4*>(&sPq[o + 8]) = q1;
    *reinterpret_cast<uint4*>(&sPk[o]) = k0; *reinterpret_cast<uint4*>(&sPk[o + 8]) = k1;
  }
  {
    int j = tid >> 2, g = tid & 3;
    const bf16* vs = vf + (size_t)(c * CS + j) * DIMM + h * HD + g * 16;
    uint4 v0 = *reinterpret_cast<const uint4*>(vs);
    uint4 v1 = *reinterpret_cast<const uint4*>(vs + 8);
    const unsigned short* pv = (const unsigned short*)&v0;
    #pragma unroll
    for (int e = 0; e < 8; e++) sVt[(g * 16 + e) * LD + j] = (short)pv[e];
    pv = (const unsigned short*)&v1;
    #pragma unroll
    for (int e = 0; e < 8; e++) sVt[(g * 16 + 8 + e) * LD + j] = (short)pv[e];
  }
  {
    int d = tid >> 2, mg = tid & 3;
    const float* src = ckv_t + ((size_t)h * NC + c) * 4096 + d * 64 + mg * 16;
    int o = d * LD + mg * 16;
    #pragma unroll
    for (int e4 = 0; e4 < 4; e4++) {
      float4 v = *reinterpret_cast<const float4*>(src + e4 * 4);
      uint2 ph, pl;
      split_pack_bf(v, ph, pl);
      *reinterpret_cast<uint2*>(&sSh[o + e4 * 4]) = ph;
      *reinterpret_cast<uint2*>(&sSl[o + e4 * 4]) = pl;
    }
  }
  if (tid < 64) sKc[tid] = ck[((size_t)h * NC + c) * FM + tid];
  __syncthreads();

  const int frow = lane & 15, fk = (lane >> 4) * 8;
  const int rowW = wv * 16;

  f32x4 accA[4];
  #pragma unroll
  for (int ct = 0; ct < 4; ct++) accA[ct] = (f32x4){0.f, 0.f, 0.f, 0.f};
  #pragma unroll
  for (int ks = 0; ks < 64; ks += 32) {
    bf16x8 a = *reinterpret_cast<const bf16x8*>(&sPq[(rowW + frow) * LD + ks + fk]);
    #pragma unroll
    for (int ct = 0; ct < 4; ct++) {
      bf16x8 b = *reinterpret_cast<const bf16x8*>(&sPk[(ct * 16 + frow) * LD + ks + fk]);
      accA[ct] = __builtin_amdgcn_mfma_f32_16x16x32_bf16(a, b, accA[ct], 0, 0, 0);
    }
  }
  __syncthreads();

  #pragma unroll
  for (int ct = 0; ct < 4; ct++)
    #pragma unroll
    for (int reg = 0; reg < 4; reg++) {
      int gi = rowW + (lane >> 4) * 4 + reg;
      int gj = ct * 16 + (lane & 15);
      float av = (gj <= gi) ? accA[ct][reg] : 0.f;
      bf16 hb = __float2bfloat16(av);
      sPk[gi * LD + gj] = *reinterpret_cast<short*>(&hb);
      unsigned short lu = f2bfu(av - b2f(hb));
      sAl[gi * LD + gj] = (short)lu;
    }
  __syncthreads();

  {
    int i = tid >> 2, q = tid & 3;
    float p = 0.f;
    #pragma unroll
    for (int e = 0; e < 16; e++) {
      int m = q * 16 + e;
      p += b2f(*reinterpret_cast<bf16*>(&sPq[i * LD + m])) * sKc[m];
      p += b2f(*reinterpret_cast<bf16*>(&sPk[i * LD + m]))
         + b2f(*reinterpret_cast<bf16*>(&sAl[i * LD + m]));
    }
    sDp[i][q] = p;
  }

  f32x4 accO[4];
  #pragma unroll
  for (int dt = 0; dt < 4; dt++) accO[dt] = (f32x4){0.f, 0.f, 0.f, 0.f};
  #pragma unroll
  for (int ks = 0; ks < 64; ks += 32) {
    bf16x8 ah = *reinterpret_cast<const bf16x8*>(&sPk[(rowW + frow) * LD + ks + fk]);
    bf16x8 al = *reinterpret_cast<const bf16x8*>(&sAl[(rowW + frow) * LD + ks + fk]);
    bf16x8 aq = *reinterpret_cast<const bf16x8*>(&sPq[(rowW + frow) * LD + ks + fk]);
    #pragma unroll
    for (int dt = 0; dt < 4; dt++) {
      bf16x8 bv = *reinterpret_cast<const bf16x8*>(&sVt[(dt * 16 + frow) * LD + ks + fk]);
      bf16x8 bh = *reinterpret_cast<const bf16x8*>(&sSh[(dt * 16 + frow) * LD + ks + fk]);
      bf16x8 bl = *reinterpret_cast<const bf16x8*>(&sSl[(dt * 16 + frow) * LD + ks + fk]);
      accO[dt] = __builtin_amdgcn_mfma_f32_16x16x32_bf16(ah, bv, accO[dt], 0, 0, 0);
      accO[dt] = __builtin_amdgcn_mfma_f32_16x16x32_bf16(al, bv, accO[dt], 0, 0, 0);
      accO[dt] = __builtin_amdgcn_mfma_f32_16x16x32_bf16(aq, bh, accO[dt], 0, 0, 0);
      accO[dt] = __builtin_amdgcn_mfma_f32_16x16x32_bf16(aq, bl, accO[dt], 0, 0, 0);
    }
  }
  __syncthreads();
  if (tid < 64) {
    float den = sDp[tid][0] + sDp[tid][1] + sDp[tid][2] + sDp[tid][3];
    sDen[tid] = 1.f / (den + 1e-6f);
  }
  __syncthreads();

  #pragma unroll
  for (int dt = 0; dt < 4; dt++)
    #pragma unroll
    for (int reg = 0; reg < 4; reg++) {
      int gi = rowW + (lane >> 4) * 4 + reg;
      int gd = dt * 16 + (lane & 15);
      float v = accO[dt][reg] * sDen[gi];
      attn_out[(size_t)(c * CS + gi) * DIMM + h * HD + gd] = __float2bfloat16(v);
    }
}

extern "C" void kernel_launch(void* const* d_in, const int* in_sizes, int n_in,
                              void* d_out, int out_size, void* d_ws, size_t ws_size,
                              hipStream_t stream) {
  (void)in_sizes; (void)n_in; (void)out_size; (void)ws_size;
  const float* x     = (const float*)d_in[0];
  const float* omega = (const float*)d_in[1];
  const float* wq    = (const float*)d_in[2];
  const float* wk    = (const float*)d_in[3];
  const float* wv    = (const float*)d_in[4];
  const float* wo    = (const float*)d_in[5];
  const float* bo    = (const float*)d_in[6];
  float* out = (float*)d_out;

  char* w = (char*)d_ws;
  _Float16* x16   = (_Float16*)(w);                  // 4 MB  [later: attn bf16 alias]
  _Float16* w16   = (_Float16*)(w + (4u  << 20));    // 6 MB
  bf16*     wo_bf = (bf16*)   (w + (10u << 20));     // 2 MB
  _Float16* qk    = (_Float16*)(w + (12u << 20));    // 8 MB
  bf16*     vbf   = (bf16*)   (w + (20u << 20));     // 4 MB
  bf16*     phiq  = (bf16*)   (w + (24u << 20));     // 4 MB
  bf16*     phik  = (bf16*)   (w + (28u << 20));     // 4 MB
  float*    ckv   = (float*)  (w + (32u << 20));     // 8 MB (transposed [d][m])
  float*    ck    = (float*)  (w + (40u << 20));     // 128 KB
  bf16*     attnb = (bf16*)x16;

  cvt_all<<<6144, 256, 0, stream>>>((const float4*)x, (const float4*)wq,
                                    (const float4*)wk, (const float4*)wv,
                                    (const float4*)wo,
                                    x16, w16, wo_bf);

  gemm_qkv_f16<<<dim3(24, 16), 512, 0, stream>>>(x16, w16, qk, vbf);

  phi_mfma<<<dim3(N_TOK / 128, NH, 2), 256, 0, stream>>>(qk, omega, phiq, phik);

  chunk_sum<<<dim3(NC, NH), 256, 0, stream>>>(phik, vbf, ckv, ck);
  prefix_chunks<<<dim3(NH, 16), 256, 0, stream>>>(ckv, ck);
  attn_chunk<<<dim3(NC, NH), 256, 0, stream>>>(phiq, phik, vbf, ckv, ck, attnb);

  gemm_bf16_out<<<dim3(8, 32), 512, 0, stream>>>(attnb, wo_bf, bo, out);
}

// Round 11
// 142.613 us; speedup vs baseline: 1.4678x; 1.0046x over previous
//
#include <hip/hip_runtime.h>
#include <hip/hip_bf16.h>

typedef __hip_bfloat16 bf16;
typedef __attribute__((ext_vector_type(8))) short bf16x8;
typedef __attribute__((ext_vector_type(8))) _Float16 f16x8;
typedef __attribute__((ext_vector_type(4))) float f32x4;

constexpr int N_TOK = 2048;
constexpr int DIMM  = 1024;
constexpr int NH    = 16;
constexpr int HD    = 64;
constexpr int FM    = 64;
constexpr int NC    = 32;
constexpr int CS    = 64;

__device__ __forceinline__ float b2f(bf16 v) { return __bfloat162float(v); }
__device__ __forceinline__ unsigned short f2bfu(float v) {
  bf16 h = __float2bfloat16(v);
  return *reinterpret_cast<unsigned short*>(&h);
}
__device__ __forceinline__ unsigned short f2hu(float v) {
  _Float16 h = (_Float16)v;
  return *reinterpret_cast<unsigned short*>(&h);
}

__device__ __forceinline__ void gl_lds16(const void* g, short* l) {
  __builtin_amdgcn_global_load_lds(
      (const __attribute__((address_space(1))) void*)g,
      (__attribute__((address_space(3))) void*)l, 16, 0, 0);
}

__device__ __forceinline__ void split_pack_bf(const float4 v, uint2& ph, uint2& pl) {
  float f[4] = {v.x, v.y, v.z, v.w};
  unsigned short h[4], l[4];
  #pragma unroll
  for (int j = 0; j < 4; j++) {
    bf16 hb = __float2bfloat16(f[j]);
    h[j] = *reinterpret_cast<unsigned short*>(&hb);
    l[j] = f2bfu(f[j] - b2f(hb));
  }
  ph.x = (unsigned)h[0] | ((unsigned)h[1] << 16);
  ph.y = (unsigned)h[2] | ((unsigned)h[3] << 16);
  pl.x = (unsigned)l[0] | ((unsigned)l[1] << 16);
  pl.y = (unsigned)l[2] | ((unsigned)l[3] << 16);
}

// Fused conversions: x -> fp16; wq|wk|wv -> fp16 [3072][1024]; wo -> bf16.
__global__ __launch_bounds__(256) void cvt_all(
    const float4* __restrict__ x, const float4* __restrict__ wq,
    const float4* __restrict__ wk, const float4* __restrict__ wv,
    const float4* __restrict__ wo,
    _Float16* __restrict__ x16, _Float16* __restrict__ w16,
    bf16* __restrict__ wo_bf)
{
  int i = blockIdx.x * 256 + threadIdx.x;   // < 1572864
  if (i < 524288) {
    float4 v = x[i];
    uint2 p = { (unsigned)f2hu(v.x) | ((unsigned)f2hu(v.y) << 16),
                (unsigned)f2hu(v.z) | ((unsigned)f2hu(v.w) << 16) };
    reinterpret_cast<uint2*>(x16)[i] = p;
  } else if (i < 1310720) {
    int j = i - 524288;
    const float4* src = (j < 262144) ? wq : (j < 524288) ? wk : wv;
    int jj = (j < 262144) ? j : (j < 524288) ? j - 262144 : j - 524288;
    float4 v = src[jj];
    uint2 p = { (unsigned)f2hu(v.x) | ((unsigned)f2hu(v.y) << 16),
                (unsigned)f2hu(v.z) | ((unsigned)f2hu(v.w) << 16) };
    reinterpret_cast<uint2*>(w16)[j] = p;
  } else {
    int j = i - 1310720;
    float4 v = wo[j];
    uint2 p = { (unsigned)f2bfu(v.x) | ((unsigned)f2bfu(v.y) << 16),
                (unsigned)f2bfu(v.z) | ((unsigned)f2bfu(v.w) << 16) };
    reinterpret_cast<uint2*>(wo_bf)[j] = p;
  }
}

// Fused QKV projection + phi feature map.
// Main GEMM: single fp16 MFMA, 128x128 tile, BK=32, dbuf 32 KB, 8 waves (64x32/wave).
// q/k blocks (colBase<2048) then compute phi = exp(q.omega^T - 0.5||q||^2)/8 in-kernel:
// the 128-col tile covers exactly 2 heads; per-head, q accs are split bf16 hi/lo into
// LDS (union with the dbuf) and a 3-product MFMA vs omega produces proj fp32-accurately.
// v blocks write vbf. LDS union = 55 KB -> 2 blocks/CU.
__global__ __launch_bounds__(512, 4) void gemm_qkv_phi(
    const _Float16* __restrict__ A16, const _Float16* __restrict__ B16,
    const float* __restrict__ omega,
    bf16* __restrict__ phiq, bf16* __restrict__ phik, bf16* __restrict__ Cv)
{
  constexpr int K = 1024;
  __shared__ alignas(16) char smemRaw[56320];
  short* sA = (short*)smemRaw;       // [2][4096] main loop
  short* sB = sA + 8192;             // [2][4096]

  const int tid = threadIdx.x, lane = tid & 63, wv = tid >> 6;   // wv 0..7
  const int colBase = blockIdx.x * 128, rowBase = blockIdx.y * 128;
  const int waveRow = (wv >> 2) * 64, waveCol = (wv & 3) * 32;
  const int stR = tid >> 2, stK = (tid & 3) * 8;

  const _Float16* gA = A16 + (size_t)(rowBase + stR) * K + stK;
  const _Float16* gB = B16 + (size_t)(colBase + stR) * K + stK;
  const int ldsOff = wv * 512;

  f32x4 acc[4][2];
  #pragma unroll
  for (int r = 0; r < 4; r++)
    #pragma unroll
    for (int c = 0; c < 2; c++) acc[r][c] = (f32x4){0.f, 0.f, 0.f, 0.f};

  const int frow = lane & 15, fk = (lane >> 4) * 8, quad = lane >> 4;
  const int nIter = K / 32;

  gl_lds16(gA, &sA[ldsOff]);
  gl_lds16(gB, &sB[ldsOff]);

  int buf = 0;
  for (int it = 0; it < nIter; it++) {
    __syncthreads();
    if (it + 1 < nIter) {
      const size_t kb = (size_t)(it + 1) * 32;
      const int nb = buf ^ 1;
      gl_lds16(gA + kb, &sA[nb * 4096 + ldsOff]);
      gl_lds16(gB + kb, &sB[nb * 4096 + ldsOff]);
    }
    f16x8 a[4], b[2];
    #pragma unroll
    for (int r = 0; r < 4; r++)
      a[r] = *reinterpret_cast<const f16x8*>(&sA[buf * 4096 + (waveRow + r * 16 + frow) * 32 + fk]);
    #pragma unroll
    for (int c = 0; c < 2; c++)
      b[c] = *reinterpret_cast<const f16x8*>(&sB[buf * 4096 + (waveCol + c * 16 + frow) * 32 + fk]);
    #pragma unroll
    for (int r = 0; r < 4; r++)
      #pragma unroll
      for (int c = 0; c < 2; c++)
        acc[r][c] = __builtin_amdgcn_mfma_f32_16x16x32_f16(a[r], b[c], acc[r][c], 0, 0, 0);
    buf ^= 1;
  }
  __syncthreads();   // all main-loop LDS reads done before union reuse / exit

  if (colBase >= 2048) {
    // V path: write bf16 vbf
    #pragma unroll
    for (int r = 0; r < 4; r++)
      #pragma unroll
      for (int c = 0; c < 2; c++)
        #pragma unroll
        for (int reg = 0; reg < 4; reg++) {
          int row = rowBase + waveRow + r * 16 + quad * 4 + reg;
          int col = colBase - 2048 + waveCol + c * 16 + (lane & 15);
          Cv[(size_t)row * 1024 + col] = __float2bfloat16(acc[r][c][reg]);
        }
    return;
  }

  // --- phi phase (q or k) ---
  constexpr int LD = 72;
  short* sQh = (short*)smemRaw;          // 128*72 shorts = 18432 B
  short* sQl = sQh + 9216;               // 18432 B
  short* sOh = sQl + 9216;               // 64*72 = 9216 B
  short* sOl = sOh + 4608;               // 9216 B
  float* sNorm = (float*)(sOl + 4608);   // [2][128] = 1024 B

  const bool isQ = (colBase < 1024);
  const int hPairBase = (isQ ? colBase : (colBase - 1024)) >> 6;
  bf16* dstBase = isQ ? phiq : phik;
  const int headSel = (wv & 3) >> 1;

  // stage omega (bf16 hi/lo split); zero norms
  {
    int r = tid >> 3, cg = (tid & 7) * 8;
    const float* src = omega + r * 64 + cg;
    float4 v0 = *reinterpret_cast<const float4*>(src);
    float4 v1 = *reinterpret_cast<const float4*>(src + 4);
    uint2 ph, pl;
    split_pack_bf(v0, ph, pl);
    *reinterpret_cast<uint2*>(&sOh[r * LD + cg])     = ph;
    *reinterpret_cast<uint2*>(&sOl[r * LD + cg])     = pl;
    split_pack_bf(v1, ph, pl);
    *reinterpret_cast<uint2*>(&sOh[r * LD + cg + 4]) = ph;
    *reinterpret_cast<uint2*>(&sOl[r * LD + cg + 4]) = pl;
  }
  if (tid < 256) sNorm[tid] = 0.f;
  __syncthreads();

  // per-row ||q||^2 partials: each lane's 2 cols, in-quad shuffle reduce, LDS atomic
  #pragma unroll
  for (int r = 0; r < 4; r++)
    #pragma unroll
    for (int reg = 0; reg < 4; reg++) {
      float s = acc[r][0][reg] * acc[r][0][reg] + acc[r][1][reg] * acc[r][1][reg];
      s += __shfl_xor(s, 1); s += __shfl_xor(s, 2);
      s += __shfl_xor(s, 4); s += __shfl_xor(s, 8);
      if ((lane & 15) == 0) {
        int row = waveRow + r * 16 + quad * 4 + reg;
        atomicAdd(&sNorm[headSel * 128 + row], s);
      }
    }

  #pragma unroll
  for (int hh = 0; hh < 2; hh++) {
    if (headSel == hh) {
      // stage this head's q tile (bf16 hi/lo from fp32 accs)
      #pragma unroll
      for (int r = 0; r < 4; r++)
        #pragma unroll
        for (int c = 0; c < 2; c++)
          #pragma unroll
          for (int reg = 0; reg < 4; reg++) {
            int row = waveRow + r * 16 + quad * 4 + reg;
            int lc = (waveCol & 63) + c * 16 + (lane & 15);
            float v = acc[r][c][reg];
            bf16 hb = __float2bfloat16(v);
            sQh[row * LD + lc] = *reinterpret_cast<short*>(&hb);
            sQl[row * LD + lc] = (short)f2bfu(v - b2f(hb));
          }
    }
    __syncthreads();

    // proj = q . omega^T  (3-product split), each wave 16 rows x 64 cols
    f32x4 acc2[4];
    #pragma unroll
    for (int ct = 0; ct < 4; ct++) acc2[ct] = (f32x4){0.f, 0.f, 0.f, 0.f};
    #pragma unroll
    for (int ks = 0; ks < 64; ks += 32) {
      bf16x8 ah = *reinterpret_cast<const bf16x8*>(&sQh[(wv * 16 + frow) * LD + ks + fk]);
      bf16x8 al = *reinterpret_cast<const bf16x8*>(&sQl[(wv * 16 + frow) * LD + ks + fk]);
      #pragma unroll
      for (int ct = 0; ct < 4; ct++) {
        bf16x8 bh = *reinterpret_cast<const bf16x8*>(&sOh[(ct * 16 + frow) * LD + ks + fk]);
        bf16x8 bl = *reinterpret_cast<const bf16x8*>(&sOl[(ct * 16 + frow) * LD + ks + fk]);
        acc2[ct] = __builtin_amdgcn_mfma_f32_16x16x32_bf16(ah, bh, acc2[ct], 0, 0, 0);
        acc2[ct] = __builtin_amdgcn_mfma_f32_16x16x32_bf16(ah, bl, acc2[ct], 0, 0, 0);
        acc2[ct] = __builtin_amdgcn_mfma_f32_16x16x32_bf16(al, bh, acc2[ct], 0, 0, 0);
      }
    }
    // phi epilogue
    const int h = hPairBase + hh;
    #pragma unroll
    for (int ct = 0; ct < 4; ct++)
      #pragma unroll
      for (int reg = 0; reg < 4; reg++) {
        int row = wv * 16 + quad * 4 + reg;
        int m = ct * 16 + (lane & 15);
        float norm = 0.5f * sNorm[hh * 128 + row];
        float v = __expf(fminf(acc2[ct][reg] - norm, 80.f)) * 0.125f;
        dstBase[((size_t)h * N_TOK + rowBase + row) * FM + m] = __float2bfloat16(v);
      }
    __syncthreads();   // before next head overwrites sQ
  }
}

// Output projection: bf16 NT GEMM + bias, fp32 out. Block 64x128, 512 threads
// = 8 waves (2x4, wave tile 32x32), dbuf LDS 24 KB. Grid (8,32)=256 blocks.
__global__ __launch_bounds__(512) void gemm_bf16_out(
    const bf16* __restrict__ A, const bf16* __restrict__ B,
    const float* __restrict__ bias, float* __restrict__ C)
{
  constexpr int K = 1024;
  __shared__ short sA[2][2048], sB[2][4096];
  const int tid = threadIdx.x, lane = tid & 63, wv = tid >> 6;
  const int rowBase = blockIdx.y * 64, colBase = blockIdx.x * 128;
  const int waveRow = (wv >> 2) * 32, waveCol = (wv & 3) * 32;
  const int stR = tid >> 2, stK = (tid & 3) * 8;
  const bf16* gA = A + (size_t)(rowBase + stR) * K + stK;   // valid for wv<4 only
  const bf16* gB = B + (size_t)(colBase + stR) * K + stK;
  const int ldsOff = wv * 512;

  f32x4 acc[2][2];
  #pragma unroll
  for (int r = 0; r < 2; r++)
    #pragma unroll
    for (int c = 0; c < 2; c++) acc[r][c] = (f32x4){0.f, 0.f, 0.f, 0.f};

  const int frow = lane & 15, fk = (lane >> 4) * 8;
  const int nIter = K / 32;

  if (wv < 4) gl_lds16(gA, &sA[0][ldsOff]);
  gl_lds16(gB, &sB[0][ldsOff]);

  int buf = 0;
  for (int it = 0; it < nIter; it++) {
    __syncthreads();
    if (it + 1 < nIter) {
      const size_t kb = (size_t)(it + 1) * 32;
      const int nb = buf ^ 1;
      if (wv < 4) gl_lds16(gA + kb, &sA[nb][ldsOff]);
      gl_lds16(gB + kb, &sB[nb][ldsOff]);
    }
    bf16x8 a[2], b[2];
    #pragma unroll
    for (int r = 0; r < 2; r++)
      a[r] = *reinterpret_cast<const bf16x8*>(&sA[buf][(waveRow + r * 16 + frow) * 32 + fk]);
    #pragma unroll
    for (int c = 0; c < 2; c++)
      b[c] = *reinterpret_cast<const bf16x8*>(&sB[buf][(waveCol + c * 16 + frow) * 32 + fk]);
    #pragma unroll
    for (int r = 0; r < 2; r++)
      #pragma unroll
      for (int c = 0; c < 2; c++)
        acc[r][c] = __builtin_amdgcn_mfma_f32_16x16x32_bf16(a[r], b[c], acc[r][c], 0, 0, 0);
    buf ^= 1;
  }

  #pragma unroll
  for (int r = 0; r < 2; r++)
    #pragma unroll
    for (int c = 0; c < 2; c++)
      #pragma unroll
      for (int reg = 0; reg < 4; reg++) {
        int row = rowBase + waveRow + r * 16 + (lane >> 4) * 4 + reg;
        int col = colBase + waveCol + c * 16 + (lane & 15);
        C[(size_t)row * 1024 + col] = acc[r][c][reg] + bias[col];
      }
}

// MFMA chunk sums: ckv_t[h][c][d][m] = sum_j v[j][d]*phik[j][m]; ck = col sums of phik.
__global__ __launch_bounds__(256) void chunk_sum(
    const bf16* __restrict__ phik, const bf16* __restrict__ vf,
    float* __restrict__ ckv_t, float* __restrict__ ck)
{
  constexpr int LD = 72;
  __shared__ short sVt[64 * LD], sPkt[64 * LD];
  __shared__ float sCp[64][4];
  const int c = blockIdx.x, h = blockIdx.y;
  const int tid = threadIdx.x, lane = tid & 63, wv = tid >> 6;

  {
    int j = tid >> 2, g = tid & 3;
    const bf16* vs = vf + (size_t)(c * CS + j) * DIMM + h * HD + g * 16;
    uint4 v0 = *reinterpret_cast<const uint4*>(vs);
    uint4 v1 = *reinterpret_cast<const uint4*>(vs + 8);
    const unsigned short* pv = (const unsigned short*)&v0;
    #pragma unroll
    for (int e = 0; e < 8; e++) sVt[(g * 16 + e) * LD + j] = (short)pv[e];
    pv = (const unsigned short*)&v1;
    #pragma unroll
    for (int e = 0; e < 8; e++) sVt[(g * 16 + 8 + e) * LD + j] = (short)pv[e];

    const bf16* ks = phik + ((size_t)h * N_TOK + c * CS + j) * FM + g * 16;
    uint4 k0 = *reinterpret_cast<const uint4*>(ks);
    uint4 k1 = *reinterpret_cast<const uint4*>(ks + 8);
    pv = (const unsigned short*)&k0;
    #pragma unroll
    for (int e = 0; e < 8; e++) sPkt[(g * 16 + e) * LD + j] = (short)pv[e];
    pv = (const unsigned short*)&k1;
    #pragma unroll
    for (int e = 0; e < 8; e++) sPkt[(g * 16 + 8 + e) * LD + j] = (short)pv[e];
  }
  __syncthreads();

  const int frow = lane & 15, fk = (lane >> 4) * 8;
  const int rowW = wv * 16;

  f32x4 acc[4];
  #pragma unroll
  for (int mt = 0; mt < 4; mt++) acc[mt] = (f32x4){0.f, 0.f, 0.f, 0.f};
  #pragma unroll
  for (int ks = 0; ks < 64; ks += 32) {
    bf16x8 a = *reinterpret_cast<const bf16x8*>(&sVt[(rowW + frow) * LD + ks + fk]);
    #pragma unroll
    for (int mt = 0; mt < 4; mt++) {
      bf16x8 b = *reinterpret_cast<const bf16x8*>(&sPkt[(mt * 16 + frow) * LD + ks + fk]);
      acc[mt] = __builtin_amdgcn_mfma_f32_16x16x32_bf16(a, b, acc[mt], 0, 0, 0);
    }
  }

  {
    int m = tid >> 2, q = tid & 3;
    float s = 0.f;
    #pragma unroll
    for (int e = 0; e < 16; e++)
      s += b2f(*reinterpret_cast<bf16*>(&sPkt[m * LD + q * 16 + e]));
    sCp[m][q] = s;
  }
  __syncthreads();
  if (tid < 64)
    ck[((size_t)h * NC + c) * FM + tid] = sCp[tid][0] + sCp[tid][1] + sCp[tid][2] + sCp[tid][3];

  float* dst = ckv_t + ((size_t)h * NC + c) * 4096;
  #pragma unroll
  for (int mt = 0; mt < 4; mt++)
    #pragma unroll
    for (int reg = 0; reg < 4; reg++) {
      int gd = rowW + (lane >> 4) * 4 + reg;
      int gm = mt * 16 + (lane & 15);
      dst[gd * 64 + gm] = acc[mt][reg];
    }
}

// Register-blocked exclusive prefix over chunks (layout-agnostic).
__global__ __launch_bounds__(256) void prefix_chunks(
    float* __restrict__ ckv, float* __restrict__ ck)
{
  const int h = blockIdx.x, g = blockIdx.y;
  const int cell = g * 256 + threadIdx.x;
  const size_t base = (size_t)h * NC * 4096 + cell;
  float v[NC];
  #pragma unroll
  for (int c = 0; c < NC; c++) v[c] = ckv[base + (size_t)c * 4096];
  float run = 0.f;
  #pragma unroll
  for (int c = 0; c < NC; c++) { float t = v[c]; ckv[base + (size_t)c * 4096] = run; run += t; }
  if (g == 0 && threadIdx.x < 64) {
    const size_t b2 = (size_t)h * NC * FM + threadIdx.x;
    float u[NC];
    #pragma unroll
    for (int c = 0; c < NC; c++) u[c] = ck[b2 + (size_t)c * FM];
    float r2 = 0.f;
    #pragma unroll
    for (int c = 0; c < NC; c++) { float t = u[c]; ck[b2 + (size_t)c * FM] = r2; r2 += t; }
  }
}

// MFMA causal chunk attention.
__global__ __launch_bounds__(256) void attn_chunk(
    const bf16* __restrict__ phiq, const bf16* __restrict__ phik,
    const bf16* __restrict__ vf, const float* __restrict__ ckv_t,
    const float* __restrict__ ck, bf16* __restrict__ attn_out)
{
  constexpr int LD = 72;
  __shared__ short sPq[64 * LD];
  __shared__ short sPk[64 * LD];
  __shared__ short sAl[64 * LD];
  __shared__ short sVt[64 * LD];
  __shared__ short sSh[64 * LD];
  __shared__ short sSl[64 * LD];
  __shared__ float sKc[64];
  __shared__ float sDp[64][4];
  __shared__ float sDen[64];

  const int c = blockIdx.x, h = blockIdx.y;
  const int tid = threadIdx.x, lane = tid & 63, wv = tid >> 6;

  {
    int r = tid >> 2, g = tid & 3;
    const size_t gb = ((size_t)h * N_TOK + c * CS + r) * FM + g * 16;
    uint4 q0 = *reinterpret_cast<const uint4*>(phiq + gb);
    uint4 q1 = *reinterpret_cast<const uint4*>(phiq + gb + 8);
    uint4 k0 = *reinterpret_cast<const uint4*>(phik + gb);
    uint4 k1 = *reinterpret_cast<const uint4*>(phik + gb + 8);
    int o = r * LD + g * 16;
    *reinterpret_cast<uint4*>(&sPq[o]) = q0; *reinterpret_cast<uint4*>(&sPq[o + 8]) = q1;
    *reinterpret_cast<uint4*>(&sPk[o]) = k0; *reinterpret_cast<uint4*>(&sPk[o + 8]) = k1;
  }
  {
    int j = tid >> 2, g = tid & 3;
    const bf16* vs = vf + (size_t)(c * CS + j) * DIMM + h * HD + g * 16;
    uint4 v0 = *reinterpret_cast<const uint4*>(vs);
    uint4 v1 = *reinterpret_cast<const uint4*>(vs + 8);
    const unsigned short* pv = (const unsigned short*)&v0;
    #pragma unroll
    for (int e = 0; e < 8; e++) sVt[(g * 16 + e) * LD + j] = (short)pv[e];
    pv = (const unsigned short*)&v1;
    #pragma unroll
    for (int e = 0; e < 8; e++) sVt[(g * 16 + 8 + e) * LD + j] = (short)pv[e];
  }
  {
    int d = tid >> 2, mg = tid & 3;
    const float* src = ckv_t + ((size_t)h * NC + c) * 4096 + d * 64 + mg * 16;
    int o = d * LD + mg * 16;
    #pragma unroll
    for (int e4 = 0; e4 < 4; e4++) {
      float4 v = *reinterpret_cast<const float4*>(src + e4 * 4);
      uint2 ph, pl;
      split_pack_bf(v, ph, pl);
      *reinterpret_cast<uint2*>(&sSh[o + e4 * 4]) = ph;
      *reinterpret_cast<uint2*>(&sSl[o + e4 * 4]) = pl;
    }
  }
  if (tid < 64) sKc[tid] = ck[((size_t)h * NC + c) * FM + tid];
  __syncthreads();

  const int frow = lane & 15, fk = (lane >> 4) * 8;
  const int rowW = wv * 16;

  f32x4 accA[4];
  #pragma unroll
  for (int ct = 0; ct < 4; ct++) accA[ct] = (f32x4){0.f, 0.f, 0.f, 0.f};
  #pragma unroll
  for (int ks = 0; ks < 64; ks += 32) {
    bf16x8 a = *reinterpret_cast<const bf16x8*>(&sPq[(rowW + frow) * LD + ks + fk]);
    #pragma unroll
    for (int ct = 0; ct < 4; ct++) {
      bf16x8 b = *reinterpret_cast<const bf16x8*>(&sPk[(ct * 16 + frow) * LD + ks + fk]);
      accA[ct] = __builtin_amdgcn_mfma_f32_16x16x32_bf16(a, b, accA[ct], 0, 0, 0);
    }
  }
  __syncthreads();

  #pragma unroll
  for (int ct = 0; ct < 4; ct++)
    #pragma unroll
    for (int reg = 0; reg < 4; reg++) {
      int gi = rowW + (lane >> 4) * 4 + reg;
      int gj = ct * 16 + (lane & 15);
      float av = (gj <= gi) ? accA[ct][reg] : 0.f;
      bf16 hb = __float2bfloat16(av);
      sPk[gi * LD + gj] = *reinterpret_cast<short*>(&hb);
      unsigned short lu = f2bfu(av - b2f(hb));
      sAl[gi * LD + gj] = (short)lu;
    }
  __syncthreads();

  {
    int i = tid >> 2, q = tid & 3;
    float p = 0.f;
    #pragma unroll
    for (int e = 0; e < 16; e++) {
      int m = q * 16 + e;
      p += b2f(*reinterpret_cast<bf16*>(&sPq[i * LD + m])) * sKc[m];
      p += b2f(*reinterpret_cast<bf16*>(&sPk[i * LD + m]))
         + b2f(*reinterpret_cast<bf16*>(&sAl[i * LD + m]));
    }
    sDp[i][q] = p;
  }

  f32x4 accO[4];
  #pragma unroll
  for (int dt = 0; dt < 4; dt++) accO[dt] = (f32x4){0.f, 0.f, 0.f, 0.f};
  #pragma unroll
  for (int ks = 0; ks < 64; ks += 32) {
    bf16x8 ah = *reinterpret_cast<const bf16x8*>(&sPk[(rowW + frow) * LD + ks + fk]);
    bf16x8 al = *reinterpret_cast<const bf16x8*>(&sAl[(rowW + frow) * LD + ks + fk]);
    bf16x8 aq = *reinterpret_cast<const bf16x8*>(&sPq[(rowW + frow) * LD + ks + fk]);
    #pragma unroll
    for (int dt = 0; dt < 4; dt++) {
      bf16x8 bv = *reinterpret_cast<const bf16x8*>(&sVt[(dt * 16 + frow) * LD + ks + fk]);
      bf16x8 bh = *reinterpret_cast<const bf16x8*>(&sSh[(dt * 16 + frow) * LD + ks + fk]);
      bf16x8 bl = *reinterpret_cast<const bf16x8*>(&sSl[(dt * 16 + frow) * LD + ks + fk]);
      accO[dt] = __builtin_amdgcn_mfma_f32_16x16x32_bf16(ah, bv, accO[dt], 0, 0, 0);
      accO[dt] = __builtin_amdgcn_mfma_f32_16x16x32_bf16(al, bv, accO[dt], 0, 0, 0);
      accO[dt] = __builtin_amdgcn_mfma_f32_16x16x32_bf16(aq, bh, accO[dt], 0, 0, 0);
      accO[dt] = __builtin_amdgcn_mfma_f32_16x16x32_bf16(aq, bl, accO[dt], 0, 0, 0);
    }
  }
  __syncthreads();
  if (tid < 64) {
    float den = sDp[tid][0] + sDp[tid][1] + sDp[tid][2] + sDp[tid][3];
    sDen[tid] = 1.f / (den + 1e-6f);
  }
  __syncthreads();

  #pragma unroll
  for (int dt = 0; dt < 4; dt++)
    #pragma unroll
    for (int reg = 0; reg < 4; reg++) {
      int gi = rowW + (lane >> 4) * 4 + reg;
      int gd = dt * 16 + (lane & 15);
      float v = accO[dt][reg] * sDen[gi];
      attn_out[(size_t)(c * CS + gi) * DIMM + h * HD + gd] = __float2bfloat16(v);
    }
}

extern "C" void kernel_launch(void* const* d_in, const int* in_sizes, int n_in,
                              void* d_out, int out_size, void* d_ws, size_t ws_size,
                              hipStream_t stream) {
  (void)in_sizes; (void)n_in; (void)out_size; (void)ws_size;
  const float* x     = (const float*)d_in[0];
  const float* omega = (const float*)d_in[1];
  const float* wq    = (const float*)d_in[2];
  const float* wk    = (const float*)d_in[3];
  const float* wv    = (const float*)d_in[4];
  const float* wo    = (const float*)d_in[5];
  const float* bo    = (const float*)d_in[6];
  float* out = (float*)d_out;

  char* w = (char*)d_ws;
  _Float16* x16   = (_Float16*)(w);                  // 4 MB  [later: attn bf16 alias]
  _Float16* w16   = (_Float16*)(w + (4u  << 20));    // 6 MB
  bf16*     wo_bf = (bf16*)   (w + (10u << 20));     // 2 MB
  bf16*     vbf   = (bf16*)   (w + (12u << 20));     // 4 MB
  bf16*     phiq  = (bf16*)   (w + (16u << 20));     // 4 MB
  bf16*     phik  = (bf16*)   (w + (20u << 20));     // 4 MB
  float*    ckv   = (float*)  (w + (24u << 20));     // 8 MB (transposed [d][m])
  float*    ck    = (float*)  (w + (32u << 20));     // 128 KB
  bf16*     attnb = (bf16*)x16;

  cvt_all<<<6144, 256, 0, stream>>>((const float4*)x, (const float4*)wq,
                                    (const float4*)wk, (const float4*)wv,
                                    (const float4*)wo,
                                    x16, w16, wo_bf);

  gemm_qkv_phi<<<dim3(24, 16), 512, 0, stream>>>(x16, w16, omega, phiq, phik, vbf);

  chunk_sum<<<dim3(NC, NH), 256, 0, stream>>>(phik, vbf, ckv, ck);
  prefix_chunks<<<dim3(NH, 16), 256, 0, stream>>>(ckv, ck);
  attn_chunk<<<dim3(NC, NH), 256, 0, stream>>>(phiq, phik, vbf, ckv, ck, attnb);

  gemm_bf16_out<<<dim3(8, 32), 512, 0, stream>>>(attnb, wo_bf, bo, out);
}

// Round 12
// 140.824 us; speedup vs baseline: 1.4865x; 1.0127x over previous
//
#include <hip/hip_runtime.h>
#include <hip/hip_bf16.h>

typedef __hip_bfloat16 bf16;
typedef __attribute__((ext_vector_type(8))) short bf16x8;
typedef __attribute__((ext_vector_type(8))) _Float16 f16x8;
typedef __attribute__((ext_vector_type(4))) float f32x4;

constexpr int N_TOK = 2048;
constexpr int DIMM  = 1024;
constexpr int NH    = 16;
constexpr int HD    = 64;
constexpr int FM    = 64;
constexpr int NC    = 32;
constexpr int CS    = 64;

__device__ __forceinline__ float b2f(bf16 v) { return __bfloat162float(v); }
__device__ __forceinline__ unsigned short f2bfu(float v) {
  bf16 h = __float2bfloat16(v);
  return *reinterpret_cast<unsigned short*>(&h);
}
__device__ __forceinline__ unsigned short f2hu(float v) {
  _Float16 h = (_Float16)v;
  return *reinterpret_cast<unsigned short*>(&h);
}

__device__ __forceinline__ void gl_lds16(const void* g, short* l) {
  __builtin_amdgcn_global_load_lds(
      (const __attribute__((address_space(1))) void*)g,
      (__attribute__((address_space(3))) void*)l, 16, 0, 0);
}

__device__ __forceinline__ void split_pack_bf(const float4 v, uint2& ph, uint2& pl) {
  float f[4] = {v.x, v.y, v.z, v.w};
  unsigned short h[4], l[4];
  #pragma unroll
  for (int j = 0; j < 4; j++) {
    bf16 hb = __float2bfloat16(f[j]);
    h[j] = *reinterpret_cast<unsigned short*>(&hb);
    l[j] = f2bfu(f[j] - b2f(hb));
  }
  ph.x = (unsigned)h[0] | ((unsigned)h[1] << 16);
  ph.y = (unsigned)h[2] | ((unsigned)h[3] << 16);
  pl.x = (unsigned)l[0] | ((unsigned)l[1] << 16);
  pl.y = (unsigned)l[2] | ((unsigned)l[3] << 16);
}

// Fused conversions: x -> fp16; wq|wk|wv -> fp16 [3072][1024]; wo -> bf16.
__global__ __launch_bounds__(256) void cvt_all(
    const float4* __restrict__ x, const float4* __restrict__ wq,
    const float4* __restrict__ wk, const float4* __restrict__ wv,
    const float4* __restrict__ wo,
    _Float16* __restrict__ x16, _Float16* __restrict__ w16,
    bf16* __restrict__ wo_bf)
{
  int i = blockIdx.x * 256 + threadIdx.x;   // < 1572864
  if (i < 524288) {
    float4 v = x[i];
    uint2 p = { (unsigned)f2hu(v.x) | ((unsigned)f2hu(v.y) << 16),
                (unsigned)f2hu(v.z) | ((unsigned)f2hu(v.w) << 16) };
    reinterpret_cast<uint2*>(x16)[i] = p;
  } else if (i < 1310720) {
    int j = i - 524288;
    const float4* src = (j < 262144) ? wq : (j < 524288) ? wk : wv;
    int jj = (j < 262144) ? j : (j < 524288) ? j - 262144 : j - 524288;
    float4 v = src[jj];
    uint2 p = { (unsigned)f2hu(v.x) | ((unsigned)f2hu(v.y) << 16),
                (unsigned)f2hu(v.z) | ((unsigned)f2hu(v.w) << 16) };
    reinterpret_cast<uint2*>(w16)[j] = p;
  } else {
    int j = i - 1310720;
    float4 v = wo[j];
    uint2 p = { (unsigned)f2bfu(v.x) | ((unsigned)f2bfu(v.y) << 16),
                (unsigned)f2bfu(v.z) | ((unsigned)f2bfu(v.w) << 16) };
    reinterpret_cast<uint2*>(wo_bf)[j] = p;
  }
}

// Fused QKV projection + phi feature map (slim 32 KB LDS union).
// Main GEMM: single fp16 MFMA, 128x128 tile, BK=32, dbuf 32 KB, 8 waves (64x32/wave).
// phi phase: q from fp32 accs -> fp16 in LDS (one head at a time), omega fp16;
// single-product fp16 MFMA (phi-arg err ~3e-4); norm exact fp32 via shuffle+atomic.
__global__ __launch_bounds__(512, 4) void gemm_qkv_phi(
    const _Float16* __restrict__ A16, const _Float16* __restrict__ B16,
    const float* __restrict__ omega,
    bf16* __restrict__ phiq, bf16* __restrict__ phik, bf16* __restrict__ Cv)
{
  constexpr int K = 1024;
  __shared__ alignas(16) char smemRaw[32768];
  short* sA = (short*)smemRaw;       // [2][4096] main loop
  short* sB = sA + 8192;             // [2][4096]

  const int tid = threadIdx.x, lane = tid & 63, wv = tid >> 6;   // wv 0..7
  const int colBase = blockIdx.x * 128, rowBase = blockIdx.y * 128;
  const int waveRow = (wv >> 2) * 64, waveCol = (wv & 3) * 32;
  const int stR = tid >> 2, stK = (tid & 3) * 8;

  const _Float16* gA = A16 + (size_t)(rowBase + stR) * K + stK;
  const _Float16* gB = B16 + (size_t)(colBase + stR) * K + stK;
  const int ldsOff = wv * 512;

  f32x4 acc[4][2];
  #pragma unroll
  for (int r = 0; r < 4; r++)
    #pragma unroll
    for (int c = 0; c < 2; c++) acc[r][c] = (f32x4){0.f, 0.f, 0.f, 0.f};

  const int frow = lane & 15, fk = (lane >> 4) * 8, quad = lane >> 4;
  const int nIter = K / 32;

  gl_lds16(gA, &sA[ldsOff]);
  gl_lds16(gB, &sB[ldsOff]);

  int buf = 0;
  for (int it = 0; it < nIter; it++) {
    __syncthreads();
    if (it + 1 < nIter) {
      const size_t kb = (size_t)(it + 1) * 32;
      const int nb = buf ^ 1;
      gl_lds16(gA + kb, &sA[nb * 4096 + ldsOff]);
      gl_lds16(gB + kb, &sB[nb * 4096 + ldsOff]);
    }
    f16x8 a[4], b[2];
    #pragma unroll
    for (int r = 0; r < 4; r++)
      a[r] = *reinterpret_cast<const f16x8*>(&sA[buf * 4096 + (waveRow + r * 16 + frow) * 32 + fk]);
    #pragma unroll
    for (int c = 0; c < 2; c++)
      b[c] = *reinterpret_cast<const f16x8*>(&sB[buf * 4096 + (waveCol + c * 16 + frow) * 32 + fk]);
    #pragma unroll
    for (int r = 0; r < 4; r++)
      #pragma unroll
      for (int c = 0; c < 2; c++)
        acc[r][c] = __builtin_amdgcn_mfma_f32_16x16x32_f16(a[r], b[c], acc[r][c], 0, 0, 0);
    buf ^= 1;
  }
  __syncthreads();   // all main-loop LDS reads done before union reuse / exit

  if (colBase >= 2048) {
    #pragma unroll
    for (int r = 0; r < 4; r++)
      #pragma unroll
      for (int c = 0; c < 2; c++)
        #pragma unroll
        for (int reg = 0; reg < 4; reg++) {
          int row = rowBase + waveRow + r * 16 + quad * 4 + reg;
          int col = colBase - 2048 + waveCol + c * 16 + (lane & 15);
          Cv[(size_t)row * 1024 + col] = __float2bfloat16(acc[r][c][reg]);
        }
    return;
  }

  // --- phi phase (q or k) --- LDS: sQ16 18432 + sO16 9216 + sNorm 1024 = 28672 B
  constexpr int LD = 72;
  short* sQ16 = (short*)smemRaw;          // [128][72] fp16, one head at a time
  short* sO16 = sQ16 + 9216;              // [64][72] fp16
  float* sNorm = (float*)(sO16 + 4608);   // [2][128]

  const bool isQ = (colBase < 1024);
  const int hPairBase = (isQ ? colBase : (colBase - 1024)) >> 6;
  bf16* dstBase = isQ ? phiq : phik;
  const int headSel = (wv & 3) >> 1;

  // stage omega fp16 (8 floats/thread -> one 16B write); zero norms
  {
    int r = tid >> 3, cg = (tid & 7) * 8;
    const float* src = omega + r * 64 + cg;
    float4 v0 = *reinterpret_cast<const float4*>(src);
    float4 v1 = *reinterpret_cast<const float4*>(src + 4);
    uint4 p = { (unsigned)f2hu(v0.x) | ((unsigned)f2hu(v0.y) << 16),
                (unsigned)f2hu(v0.z) | ((unsigned)f2hu(v0.w) << 16),
                (unsigned)f2hu(v1.x) | ((unsigned)f2hu(v1.y) << 16),
                (unsigned)f2hu(v1.z) | ((unsigned)f2hu(v1.w) << 16) };
    *reinterpret_cast<uint4*>(&sO16[r * LD + cg]) = p;
  }
  if (tid < 256) sNorm[tid] = 0.f;
  __syncthreads();

  // per-row ||q||^2 partials: in-quad shuffle reduce, LDS atomic (exact fp32)
  #pragma unroll
  for (int r = 0; r < 4; r++)
    #pragma unroll
    for (int reg = 0; reg < 4; reg++) {
      float s = acc[r][0][reg] * acc[r][0][reg] + acc[r][1][reg] * acc[r][1][reg];
      s += __shfl_xor(s, 1); s += __shfl_xor(s, 2);
      s += __shfl_xor(s, 4); s += __shfl_xor(s, 8);
      if ((lane & 15) == 0) {
        int row = waveRow + r * 16 + quad * 4 + reg;
        atomicAdd(&sNorm[headSel * 128 + row], s);
      }
    }

  #pragma unroll
  for (int hh = 0; hh < 2; hh++) {
    if (headSel == hh) {
      // stage this head's q tile as fp16 from fp32 accs
      #pragma unroll
      for (int r = 0; r < 4; r++)
        #pragma unroll
        for (int c = 0; c < 2; c++)
          #pragma unroll
          for (int reg = 0; reg < 4; reg++) {
            int row = waveRow + r * 16 + quad * 4 + reg;
            int lc = (waveCol & 63) + c * 16 + (lane & 15);
            sQ16[row * LD + lc] = (short)f2hu(acc[r][c][reg]);
          }
    }
    __syncthreads();

    // proj = q . omega^T, single fp16 MFMA product; wave wv does rows wv*16..+15
    f32x4 acc2[4];
    #pragma unroll
    for (int ct = 0; ct < 4; ct++) acc2[ct] = (f32x4){0.f, 0.f, 0.f, 0.f};
    #pragma unroll
    for (int ks = 0; ks < 64; ks += 32) {
      f16x8 a = *reinterpret_cast<const f16x8*>(&sQ16[(wv * 16 + frow) * LD + ks + fk]);
      #pragma unroll
      for (int ct = 0; ct < 4; ct++) {
        f16x8 b = *reinterpret_cast<const f16x8*>(&sO16[(ct * 16 + frow) * LD + ks + fk]);
        acc2[ct] = __builtin_amdgcn_mfma_f32_16x16x32_f16(a, b, acc2[ct], 0, 0, 0);
      }
    }
    // phi epilogue
    const int h = hPairBase + hh;
    #pragma unroll
    for (int ct = 0; ct < 4; ct++)
      #pragma unroll
      for (int reg = 0; reg < 4; reg++) {
        int row = wv * 16 + quad * 4 + reg;
        int m = ct * 16 + (lane & 15);
        float norm = 0.5f * sNorm[hh * 128 + row];
        float v = __expf(fminf(acc2[ct][reg] - norm, 80.f)) * 0.125f;
        dstBase[((size_t)h * N_TOK + rowBase + row) * FM + m] = __float2bfloat16(v);
      }
    __syncthreads();   // before next head overwrites sQ16
  }
}

// Output projection: bf16 NT GEMM + bias, fp32 out. Block 64x128, 512 threads
// = 8 waves (2x4, wave tile 32x32), dbuf LDS 24 KB. Grid (8,32)=256 blocks.
__global__ __launch_bounds__(512) void gemm_bf16_out(
    const bf16* __restrict__ A, const bf16* __restrict__ B,
    const float* __restrict__ bias, float* __restrict__ C)
{
  constexpr int K = 1024;
  __shared__ short sA[2][2048], sB[2][4096];
  const int tid = threadIdx.x, lane = tid & 63, wv = tid >> 6;
  const int rowBase = blockIdx.y * 64, colBase = blockIdx.x * 128;
  const int waveRow = (wv >> 2) * 32, waveCol = (wv & 3) * 32;
  const int stR = tid >> 2, stK = (tid & 3) * 8;
  const bf16* gA = A + (size_t)(rowBase + stR) * K + stK;   // valid for wv<4 only
  const bf16* gB = B + (size_t)(colBase + stR) * K + stK;
  const int ldsOff = wv * 512;

  f32x4 acc[2][2];
  #pragma unroll
  for (int r = 0; r < 2; r++)
    #pragma unroll
    for (int c = 0; c < 2; c++) acc[r][c] = (f32x4){0.f, 0.f, 0.f, 0.f};

  const int frow = lane & 15, fk = (lane >> 4) * 8;
  const int nIter = K / 32;

  if (wv < 4) gl_lds16(gA, &sA[0][ldsOff]);
  gl_lds16(gB, &sB[0][ldsOff]);

  int buf = 0;
  for (int it = 0; it < nIter; it++) {
    __syncthreads();
    if (it + 1 < nIter) {
      const size_t kb = (size_t)(it + 1) * 32;
      const int nb = buf ^ 1;
      if (wv < 4) gl_lds16(gA + kb, &sA[nb][ldsOff]);
      gl_lds16(gB + kb, &sB[nb][ldsOff]);
    }
    bf16x8 a[2], b[2];
    #pragma unroll
    for (int r = 0; r < 2; r++)
      a[r] = *reinterpret_cast<const bf16x8*>(&sA[buf][(waveRow + r * 16 + frow) * 32 + fk]);
    #pragma unroll
    for (int c = 0; c < 2; c++)
      b[c] = *reinterpret_cast<const bf16x8*>(&sB[buf][(waveCol + c * 16 + frow) * 32 + fk]);
    #pragma unroll
    for (int r = 0; r < 2; r++)
      #pragma unroll
      for (int c = 0; c < 2; c++)
        acc[r][c] = __builtin_amdgcn_mfma_f32_16x16x32_bf16(a[r], b[c], acc[r][c], 0, 0, 0);
    buf ^= 1;
  }

  #pragma unroll
  for (int r = 0; r < 2; r++)
    #pragma unroll
    for (int c = 0; c < 2; c++)
      #pragma unroll
      for (int reg = 0; reg < 4; reg++) {
        int row = rowBase + waveRow + r * 16 + (lane >> 4) * 4 + reg;
        int col = colBase + waveCol + c * 16 + (lane & 15);
        C[(size_t)row * 1024 + col] = acc[r][c][reg] + bias[col];
      }
}

// MFMA chunk sums: ckv_t[h][c][d][m] = sum_j v[j][d]*phik[j][m]; ck = col sums of phik.
__global__ __launch_bounds__(256) void chunk_sum(
    const bf16* __restrict__ phik, const bf16* __restrict__ vf,
    float* __restrict__ ckv_t, float* __restrict__ ck)
{
  constexpr int LD = 72;
  __shared__ short sVt[64 * LD], sPkt[64 * LD];
  __shared__ float sCp[64][4];
  const int c = blockIdx.x, h = blockIdx.y;
  const int tid = threadIdx.x, lane = tid & 63, wv = tid >> 6;

  {
    int j = tid >> 2, g = tid & 3;
    const bf16* vs = vf + (size_t)(c * CS + j) * DIMM + h * HD + g * 16;
    uint4 v0 = *reinterpret_cast<const uint4*>(vs);
    uint4 v1 = *reinterpret_cast<const uint4*>(vs + 8);
    const unsigned short* pv = (const unsigned short*)&v0;
    #pragma unroll
    for (int e = 0; e < 8; e++) sVt[(g * 16 + e) * LD + j] = (short)pv[e];
    pv = (const unsigned short*)&v1;
    #pragma unroll
    for (int e = 0; e < 8; e++) sVt[(g * 16 + 8 + e) * LD + j] = (short)pv[e];

    const bf16* ks = phik + ((size_t)h * N_TOK + c * CS + j) * FM + g * 16;
    uint4 k0 = *reinterpret_cast<const uint4*>(ks);
    uint4 k1 = *reinterpret_cast<const uint4*>(ks + 8);
    pv = (const unsigned short*)&k0;
    #pragma unroll
    for (int e = 0; e < 8; e++) sPkt[(g * 16 + e) * LD + j] = (short)pv[e];
    pv = (const unsigned short*)&k1;
    #pragma unroll
    for (int e = 0; e < 8; e++) sPkt[(g * 16 + 8 + e) * LD + j] = (short)pv[e];
  }
  __syncthreads();

  const int frow = lane & 15, fk = (lane >> 4) * 8;
  const int rowW = wv * 16;

  f32x4 acc[4];
  #pragma unroll
  for (int mt = 0; mt < 4; mt++) acc[mt] = (f32x4){0.f, 0.f, 0.f, 0.f};
  #pragma unroll
  for (int ks = 0; ks < 64; ks += 32) {
    bf16x8 a = *reinterpret_cast<const bf16x8*>(&sVt[(rowW + frow) * LD + ks + fk]);
    #pragma unroll
    for (int mt = 0; mt < 4; mt++) {
      bf16x8 b = *reinterpret_cast<const bf16x8*>(&sPkt[(mt * 16 + frow) * LD + ks + fk]);
      acc[mt] = __builtin_amdgcn_mfma_f32_16x16x32_bf16(a, b, acc[mt], 0, 0, 0);
    }
  }

  {
    int m = tid >> 2, q = tid & 3;
    float s = 0.f;
    #pragma unroll
    for (int e = 0; e < 16; e++)
      s += b2f(*reinterpret_cast<bf16*>(&sPkt[m * LD + q * 16 + e]));
    sCp[m][q] = s;
  }
  __syncthreads();
  if (tid < 64)
    ck[((size_t)h * NC + c) * FM + tid] = sCp[tid][0] + sCp[tid][1] + sCp[tid][2] + sCp[tid][3];

  float* dst = ckv_t + ((size_t)h * NC + c) * 4096;
  #pragma unroll
  for (int mt = 0; mt < 4; mt++)
    #pragma unroll
    for (int reg = 0; reg < 4; reg++) {
      int gd = rowW + (lane >> 4) * 4 + reg;
      int gm = mt * 16 + (lane & 15);
      dst[gd * 64 + gm] = acc[mt][reg];
    }
}

// Register-blocked exclusive prefix over chunks (layout-agnostic).
__global__ __launch_bounds__(256) void prefix_chunks(
    float* __restrict__ ckv, float* __restrict__ ck)
{
  const int h = blockIdx.x, g = blockIdx.y;
  const int cell = g * 256 + threadIdx.x;
  const size_t base = (size_t)h * NC * 4096 + cell;
  float v[NC];
  #pragma unroll
  for (int c = 0; c < NC; c++) v[c] = ckv[base + (size_t)c * 4096];
  float run = 0.f;
  #pragma unroll
  for (int c = 0; c < NC; c++) { float t = v[c]; ckv[base + (size_t)c * 4096] = run; run += t; }
  if (g == 0 && threadIdx.x < 64) {
    const size_t b2 = (size_t)h * NC * FM + threadIdx.x;
    float u[NC];
    #pragma unroll
    for (int c = 0; c < NC; c++) u[c] = ck[b2 + (size_t)c * FM];
    float r2 = 0.f;
    #pragma unroll
    for (int c = 0; c < NC; c++) { float t = u[c]; ck[b2 + (size_t)c * FM] = r2; r2 += t; }
  }
}

// MFMA causal chunk attention.
__global__ __launch_bounds__(256) void attn_chunk(
    const bf16* __restrict__ phiq, const bf16* __restrict__ phik,
    const bf16* __restrict__ vf, const float* __restrict__ ckv_t,
    const float* __restrict__ ck, bf16* __restrict__ attn_out)
{
  constexpr int LD = 72;
  __shared__ short sPq[64 * LD];
  __shared__ short sPk[64 * LD];
  __shared__ short sAl[64 * LD];
  __shared__ short sVt[64 * LD];
  __shared__ short sSh[64 * LD];
  __shared__ short sSl[64 * LD];
  __shared__ float sKc[64];
  __shared__ float sDp[64][4];
  __shared__ float sDen[64];

  const int c = blockIdx.x, h = blockIdx.y;
  const int tid = threadIdx.x, lane = tid & 63, wv = tid >> 6;

  {
    int r = tid >> 2, g = tid & 3;
    const size_t gb = ((size_t)h * N_TOK + c * CS + r) * FM + g * 16;
    uint4 q0 = *reinterpret_cast<const uint4*>(phiq + gb);
    uint4 q1 = *reinterpret_cast<const uint4*>(phiq + gb + 8);
    uint4 k0 = *reinterpret_cast<const uint4*>(phik + gb);
    uint4 k1 = *reinterpret_cast<const uint4*>(phik + gb + 8);
    int o = r * LD + g * 16;
    *reinterpret_cast<uint4*>(&sPq[o]) = q0; *reinterpret_cast<uint4*>(&sPq[o + 8]) = q1;
    *reinterpret_cast<uint4*>(&sPk[o]) = k0; *reinterpret_cast<uint4*>(&sPk[o + 8]) = k1;
  }
  {
    int j = tid >> 2, g = tid & 3;
    const bf16* vs = vf + (size_t)(c * CS + j) * DIMM + h * HD + g * 16;
    uint4 v0 = *reinterpret_cast<const uint4*>(vs);
    uint4 v1 = *reinterpret_cast<const uint4*>(vs + 8);
    const unsigned short* pv = (const unsigned short*)&v0;
    #pragma unroll
    for (int e = 0; e < 8; e++) sVt[(g * 16 + e) * LD + j] = (short)pv[e];
    pv = (const unsigned short*)&v1;
    #pragma unroll
    for (int e = 0; e < 8; e++) sVt[(g * 16 + 8 + e) * LD + j] = (short)pv[e];
  }
  {
    int d = tid >> 2, mg = tid & 3;
    const float* src = ckv_t + ((size_t)h * NC + c) * 4096 + d * 64 + mg * 16;
    int o = d * LD + mg * 16;
    #pragma unroll
    for (int e4 = 0; e4 < 4; e4++) {
      float4 v = *reinterpret_cast<const float4*>(src + e4 * 4);
      uint2 ph, pl;
      split_pack_bf(v, ph, pl);
      *reinterpret_cast<uint2*>(&sSh[o + e4 * 4]) = ph;
      *reinterpret_cast<uint2*>(&sSl[o + e4 * 4]) = pl;
    }
  }
  if (tid < 64) sKc[tid] = ck[((size_t)h * NC + c) * FM + tid];
  __syncthreads();

  const int frow = lane & 15, fk = (lane >> 4) * 8;
  const int rowW = wv * 16;

  f32x4 accA[4];
  #pragma unroll
  for (int ct = 0; ct < 4; ct++) accA[ct] = (f32x4){0.f, 0.f, 0.f, 0.f};
  #pragma unroll
  for (int ks = 0; ks < 64; ks += 32) {
    bf16x8 a = *reinterpret_cast<const bf16x8*>(&sPq[(rowW + frow) * LD + ks + fk]);
    #pragma unroll
    for (int ct = 0; ct < 4; ct++) {
      bf16x8 b = *reinterpret_cast<const bf16x8*>(&sPk[(ct * 16 + frow) * LD + ks + fk]);
      accA[ct] = __builtin_amdgcn_mfma_f32_16x16x32_bf16(a, b, accA[ct], 0, 0, 0);
    }
  }
  __syncthreads();

  #pragma unroll
  for (int ct = 0; ct < 4; ct++)
    #pragma unroll
    for (int reg = 0; reg < 4; reg++) {
      int gi = rowW + (lane >> 4) * 4 + reg;
      int gj = ct * 16 + (lane & 15);
      float av = (gj <= gi) ? accA[ct][reg] : 0.f;
      bf16 hb = __float2bfloat16(av);
      sPk[gi * LD + gj] = *reinterpret_cast<short*>(&hb);
      unsigned short lu = f2bfu(av - b2f(hb));
      sAl[gi * LD + gj] = (short)lu;
    }
  __syncthreads();

  {
    int i = tid >> 2, q = tid & 3;
    float p = 0.f;
    #pragma unroll
    for (int e = 0; e < 16; e++) {
      int m = q * 16 + e;
      p += b2f(*reinterpret_cast<bf16*>(&sPq[i * LD + m])) * sKc[m];
      p += b2f(*reinterpret_cast<bf16*>(&sPk[i * LD + m]))
         + b2f(*reinterpret_cast<bf16*>(&sAl[i * LD + m]));
    }
    sDp[i][q] = p;
  }

  f32x4 accO[4];
  #pragma unroll
  for (int dt = 0; dt < 4; dt++) accO[dt] = (f32x4){0.f, 0.f, 0.f, 0.f};
  #pragma unroll
  for (int ks = 0; ks < 64; ks += 32) {
    bf16x8 ah = *reinterpret_cast<const bf16x8*>(&sPk[(rowW + frow) * LD + ks + fk]);
    bf16x8 al = *reinterpret_cast<const bf16x8*>(&sAl[(rowW + frow) * LD + ks + fk]);
    bf16x8 aq = *reinterpret_cast<const bf16x8*>(&sPq[(rowW + frow) * LD + ks + fk]);
    #pragma unroll
    for (int dt = 0; dt < 4; dt++) {
      bf16x8 bv = *reinterpret_cast<const bf16x8*>(&sVt[(dt * 16 + frow) * LD + ks + fk]);
      bf16x8 bh = *reinterpret_cast<const bf16x8*>(&sSh[(dt * 16 + frow) * LD + ks + fk]);
      bf16x8 bl = *reinterpret_cast<const bf16x8*>(&sSl[(dt * 16 + frow) * LD + ks + fk]);
      accO[dt] = __builtin_amdgcn_mfma_f32_16x16x32_bf16(ah, bv, accO[dt], 0, 0, 0);
      accO[dt] = __builtin_amdgcn_mfma_f32_16x16x32_bf16(al, bv, accO[dt], 0, 0, 0);
      accO[dt] = __builtin_amdgcn_mfma_f32_16x16x32_bf16(aq, bh, accO[dt], 0, 0, 0);
      accO[dt] = __builtin_amdgcn_mfma_f32_16x16x32_bf16(aq, bl, accO[dt], 0, 0, 0);
    }
  }
  __syncthreads();
  if (tid < 64) {
    float den = sDp[tid][0] + sDp[tid][1] + sDp[tid][2] + sDp[tid][3];
    sDen[tid] = 1.f / (den + 1e-6f);
  }
  __syncthreads();

  #pragma unroll
  for (int dt = 0; dt < 4; dt++)
    #pragma unroll
    for (int reg = 0; reg < 4; reg++) {
      int gi = rowW + (lane >> 4) * 4 + reg;
      int gd = dt * 16 + (lane & 15);
      float v = accO[dt][reg] * sDen[gi];
      attn_out[(size_t)(c * CS + gi) * DIMM + h * HD + gd] = __float2bfloat16(v);
    }
}

extern "C" void kernel_launch(void* const* d_in, const int* in_sizes, int n_in,
                              void* d_out, int out_size, void* d_ws, size_t ws_size,
                              hipStream_t stream) {
  (void)in_sizes; (void)n_in; (void)out_size; (void)ws_size;
  const float* x     = (const float*)d_in[0];
  const float* omega = (const float*)d_in[1];
  const float* wq    = (const float*)d_in[2];
  const float* wk    = (const float*)d_in[3];
  const float* wv    = (const float*)d_in[4];
  const float* wo    = (const float*)d_in[5];
  const float* bo    = (const float*)d_in[6];
  float* out = (float*)d_out;

  char* w = (char*)d_ws;
  _Float16* x16   = (_Float16*)(w);                  // 4 MB  [later: attn bf16 alias]
  _Float16* w16   = (_Float16*)(w + (4u  << 20));    // 6 MB
  bf16*     wo_bf = (bf16*)   (w + (10u << 20));     // 2 MB
  bf16*     vbf   = (bf16*)   (w + (12u << 20));     // 4 MB
  bf16*     phiq  = (bf16*)   (w + (16u << 20));     // 4 MB
  bf16*     phik  = (bf16*)   (w + (20u << 20));     // 4 MB
  float*    ckv   = (float*)  (w + (24u << 20));     // 8 MB (transposed [d][m])
  float*    ck    = (float*)  (w + (32u << 20));     // 128 KB
  bf16*     attnb = (bf16*)x16;

  cvt_all<<<6144, 256, 0, stream>>>((const float4*)x, (const float4*)wq,
                                    (const float4*)wk, (const float4*)wv,
                                    (const float4*)wo,
                                    x16, w16, wo_bf);

  gemm_qkv_phi<<<dim3(24, 16), 512, 0, stream>>>(x16, w16, omega, phiq, phik, vbf);

  chunk_sum<<<dim3(NC, NH), 256, 0, stream>>>(phik, vbf, ckv, ck);
  prefix_chunks<<<dim3(NH, 16), 256, 0, stream>>>(ckv, ck);
  attn_chunk<<<dim3(NC, NH), 256, 0, stream>>>(phiq, phik, vbf, ckv, ck, attnb);

  gemm_bf16_out<<<dim3(8, 32), 512, 0, stream>>>(attnb, wo_bf, bo, out);
}